// Round 1
// baseline (4242.170 us; speedup 1.0000x reference)
//
#include <hip/hip_runtime.h>
#include <math.h>

// 3-layer GAT, fp32. N=50000, E=800000 (+N self loops), H=4 heads.
// Layers 1,2: C=32 (HC=128). Layer 3: C=10, mean over heads.
// Workspace layout (floats): bufX[N*128] Hb[N*128] LIN[N*128] ACC[N*128]
//   asrc[N*4] adst[N*4] den[N*4] mord[N*4 u32] EP[(E+N)*4]  ~= 119.2 MB

#define HEADS 4

__device__ __forceinline__ float lrelu(float v) { return v > 0.f ? v : 0.2f * v; }

// monotonic float<->uint mapping for atomicMax on floats (any sign)
__device__ __forceinline__ unsigned f2ord(float f) {
    unsigned b = __float_as_uint(f);
    return (b & 0x80000000u) ? ~b : (b | 0x80000000u);
}
__device__ __forceinline__ float ord2f(unsigned u) {
    unsigned b = (u & 0x80000000u) ? (u ^ 0x80000000u) : ~u;
    return __uint_as_float(b);
}

// ---------------- GEMM: C = A[nrows x 128] @ B[128 x M] ----------------
// BM=BN=128, BK=8, 256 threads, 8x8 thread tile. K fixed at 128.
__global__ __launch_bounds__(256) void sgemm128(const float* __restrict__ A,
                                                const float* __restrict__ B,
                                                float* __restrict__ C,
                                                int nrows, int M) {
    __shared__ float As[8][128];
    __shared__ float Bs[8][128];
    const int tid  = threadIdx.x;
    const int row0 = blockIdx.y * 128;
    const int col0 = blockIdx.x * 128;
    const int tr   = tid >> 4;   // 0..15
    const int tc   = tid & 15;   // 0..15
    const int arow = tid >> 1;   // 0..127
    const int ahalf = tid & 1;   // 0..1

    float acc[8][8];
#pragma unroll
    for (int i = 0; i < 8; ++i)
#pragma unroll
        for (int j = 0; j < 8; ++j) acc[i][j] = 0.f;

    for (int k0 = 0; k0 < 128; k0 += 8) {
        // A tile: 128 rows x 8 k, one float4 per thread
        {
            int gr = row0 + arow;
            float4 v = make_float4(0.f, 0.f, 0.f, 0.f);
            if (gr < nrows) v = *(const float4*)&A[(size_t)gr * 128 + k0 + ahalf * 4];
            As[ahalf * 4 + 0][arow] = v.x;
            As[ahalf * 4 + 1][arow] = v.y;
            As[ahalf * 4 + 2][arow] = v.z;
            As[ahalf * 4 + 3][arow] = v.w;
        }
        // B tile: 8 k x 128 cols, guarded scalar (M may be 10/40)
#pragma unroll
        for (int i = tid; i < 8 * 128; i += 256) {
            int r = i >> 7, c = i & 127;
            int gc = col0 + c;
            Bs[r][c] = (gc < M) ? B[(size_t)(k0 + r) * M + gc] : 0.f;
        }
        __syncthreads();
#pragma unroll
        for (int k = 0; k < 8; ++k) {
            float a[8], b[8];
            *(float4*)&a[0] = *(const float4*)&As[k][tr * 8];
            *(float4*)&a[4] = *(const float4*)&As[k][tr * 8 + 4];
            *(float4*)&b[0] = *(const float4*)&Bs[k][tc * 8];
            *(float4*)&b[4] = *(const float4*)&Bs[k][tc * 8 + 4];
#pragma unroll
            for (int i = 0; i < 8; ++i)
#pragma unroll
                for (int j = 0; j < 8; ++j) acc[i][j] = fmaf(a[i], b[j], acc[i][j]);
        }
        __syncthreads();
    }

#pragma unroll
    for (int i = 0; i < 8; ++i) {
        int gr = row0 + tr * 8 + i;
        if (gr >= nrows) continue;
        int gc0 = col0 + tc * 8;
        if (gc0 + 7 < M) {
            *(float4*)&C[(size_t)gr * M + gc0]     = make_float4(acc[i][0], acc[i][1], acc[i][2], acc[i][3]);
            *(float4*)&C[(size_t)gr * M + gc0 + 4] = make_float4(acc[i][4], acc[i][5], acc[i][6], acc[i][7]);
        } else {
#pragma unroll
            for (int j = 0; j < 8; ++j) {
                int gc = gc0 + j;
                if (gc < M) C[(size_t)gr * M + gc] = acc[i][j];
            }
        }
    }
}

// ---------------- per-node attention coefficients ----------------
// asrc[n,h] = sum_c Hm[n,h,c]*a_s[h,c] ; adst likewise
__global__ void alpha_kernel(const float* __restrict__ Hm,
                             const float* __restrict__ a_s,
                             const float* __restrict__ a_d,
                             float* __restrict__ asrc, float* __restrict__ adst,
                             int n, int C) {
    int idx = blockIdx.x * blockDim.x + threadIdx.x;
    if (idx >= n * HEADS) return;
    int node = idx >> 2, h = idx & 3;
    const float* row = Hm + (size_t)node * (HEADS * C) + h * C;
    const float* as = a_s + h * C;
    const float* ad = a_d + h * C;
    float s = 0.f, d = 0.f;
    for (int c = 0; c < C; ++c) {
        float v = row[c];
        s = fmaf(v, as[c], s);
        d = fmaf(v, ad[c], d);
    }
    asrc[idx] = s;
    adst[idx] = d;
}

// ---------------- edge pass 1: logits + segment max ----------------
__global__ void edge_max(const int* __restrict__ ei, int E, int ET,
                         const float* __restrict__ asrc, const float* __restrict__ adst,
                         float* __restrict__ EP, unsigned* __restrict__ mord) {
    int e = blockIdx.x * blockDim.x + threadIdx.x;
    if (e >= ET) return;
    int s, d;
    if (e < E) { s = ei[e]; d = ei[E + e]; } else { s = d = e - E; }
    float4 av = *(const float4*)&asrc[(size_t)s * 4];
    float4 dv = *(const float4*)&adst[(size_t)d * 4];
    float4 ev;
    ev.x = lrelu(av.x + dv.x);
    ev.y = lrelu(av.y + dv.y);
    ev.z = lrelu(av.z + dv.z);
    ev.w = lrelu(av.w + dv.w);
    *(float4*)&EP[(size_t)e * 4] = ev;
    unsigned* mp = mord + (size_t)d * 4;
    atomicMax(mp + 0, f2ord(ev.x));
    atomicMax(mp + 1, f2ord(ev.y));
    atomicMax(mp + 2, f2ord(ev.z));
    atomicMax(mp + 3, f2ord(ev.w));
}

// ---------------- edge pass 2: p = exp(e - m), segment sum ----------------
__global__ void edge_sum(const int* __restrict__ ei, int E, int ET,
                         float* __restrict__ EP, const unsigned* __restrict__ mord,
                         float* __restrict__ den) {
    int e = blockIdx.x * blockDim.x + threadIdx.x;
    if (e >= ET) return;
    int d = (e < E) ? ei[E + e] : e - E;
    float4 ev = *(const float4*)&EP[(size_t)e * 4];
    const unsigned* mp = mord + (size_t)d * 4;
    float4 p;
    p.x = expf(ev.x - ord2f(mp[0]));
    p.y = expf(ev.y - ord2f(mp[1]));
    p.z = expf(ev.z - ord2f(mp[2]));
    p.w = expf(ev.w - ord2f(mp[3]));
    *(float4*)&EP[(size_t)e * 4] = p;
    float* dp = den + (size_t)d * 4;
    atomicAdd(dp + 0, p.x);
    atomicAdd(dp + 1, p.y);
    atomicAdd(dp + 2, p.z);
    atomicAdd(dp + 3, p.w);
}

// ---------------- edge pass 3: ACC[dst] += p * Hm[src], HC=128 ----------------
// 32 threads per edge, float4 per thread
__global__ void edge_scatter128(const int* __restrict__ ei, int E, int ET,
                                const float* __restrict__ EP,
                                const float* __restrict__ Hm,
                                float* __restrict__ ACC) {
    int t = blockIdx.x * blockDim.x + threadIdx.x;
    int e = t >> 5;
    if (e >= ET) return;
    int g = t & 31;   // channel chunk: [g*4, g*4+4)
    int s, d;
    if (e < E) { s = ei[e]; d = ei[E + e]; } else { s = d = e - E; }
    int head = g >> 3;
    float p = EP[(size_t)e * 4 + head];
    float4 hv = *(const float4*)&Hm[(size_t)s * 128 + g * 4];
    float* out = &ACC[(size_t)d * 128 + g * 4];
    atomicAdd(out + 0, p * hv.x);
    atomicAdd(out + 1, p * hv.y);
    atomicAdd(out + 2, p * hv.z);
    atomicAdd(out + 3, p * hv.w);
}

// ---------------- edge pass 3 for layer 3 (HC=40) ----------------
__global__ void edge_scatter40(const int* __restrict__ ei, int E, int ET,
                               const float* __restrict__ EP,
                               const float* __restrict__ Hm,
                               float* __restrict__ ACC) {
    int t = blockIdx.x * blockDim.x + threadIdx.x;
    int e = t / 40;
    if (e >= ET) return;
    int c = t - e * 40;
    int s, d;
    if (e < E) { s = ei[e]; d = ei[E + e]; } else { s = d = e - E; }
    int head = c / 10;
    float p = EP[(size_t)e * 4 + head];
    float v = Hm[(size_t)s * 40 + c];
    atomicAdd(&ACC[(size_t)d * 40 + c], p * v);
}

// ---------------- epilogue layers 1,2: elu(acc/den + b + lin + lb) ----------------
__global__ void epilogue12(const float* __restrict__ ACC, const float* __restrict__ den,
                           const float* __restrict__ b, const float* __restrict__ LIN,
                           const float* __restrict__ lb, float* __restrict__ xout, int n) {
    int idx = blockIdx.x * blockDim.x + threadIdx.x;
    if (idx >= n * 128) return;
    int node = idx >> 7, j = idx & 127, h = j >> 5;
    float v = ACC[idx] / (den[(size_t)node * 4 + h] + 1e-16f) + b[j] + LIN[idx] + lb[j];
    xout[idx] = v > 0.f ? v : expf(v) - 1.f;
}

// ---------------- epilogue layer 3: mean over heads + b3 + lin ----------------
__global__ void epilogue3(const float* __restrict__ ACC, const float* __restrict__ den,
                          const float* __restrict__ b, const float* __restrict__ LIN,
                          const float* __restrict__ lb, float* __restrict__ out, int n) {
    int idx = blockIdx.x * blockDim.x + threadIdx.x;
    if (idx >= n * 10) return;
    int node = idx / 10;
    int c = idx - node * 10;
    float sum = 0.f;
#pragma unroll
    for (int h = 0; h < 4; ++h)
        sum += ACC[(size_t)node * 40 + h * 10 + c] / (den[(size_t)node * 4 + h] + 1e-16f);
    out[idx] = 0.25f * sum + b[c] + LIN[idx] + lb[c];
}

extern "C" void kernel_launch(void* const* d_in, const int* in_sizes, int n_in,
                              void* d_out, int out_size, void* d_ws, size_t ws_size,
                              hipStream_t stream) {
    const float* x   = (const float*)d_in[0];
    const int*   ei  = (const int*)d_in[1];
    const float* W1  = (const float*)d_in[2];
    const float* a1s = (const float*)d_in[3];
    const float* a1d = (const float*)d_in[4];
    const float* b1  = (const float*)d_in[5];
    const float* l1W = (const float*)d_in[6];
    const float* l1b = (const float*)d_in[7];
    const float* W2  = (const float*)d_in[8];
    const float* a2s = (const float*)d_in[9];
    const float* a2d = (const float*)d_in[10];
    const float* b2  = (const float*)d_in[11];
    const float* l2W = (const float*)d_in[12];
    const float* l2b = (const float*)d_in[13];
    const float* W3  = (const float*)d_in[14];
    const float* a3s = (const float*)d_in[15];
    const float* a3d = (const float*)d_in[16];
    const float* b3  = (const float*)d_in[17];
    const float* l3W = (const float*)d_in[18];
    const float* l3b = (const float*)d_in[19];

    const int N  = in_sizes[0] / 128;
    const int E  = in_sizes[1] / 2;
    const int ET = E + N;

    float* bufX = (float*)d_ws;
    float* Hb   = bufX + (size_t)N * 128;
    float* LIN  = Hb + (size_t)N * 128;
    float* ACC  = LIN + (size_t)N * 128;
    float* asrc = ACC + (size_t)N * 128;
    float* adst = asrc + (size_t)N * 4;
    float* den  = adst + (size_t)N * 4;
    unsigned* mord = (unsigned*)(den + (size_t)N * 4);
    float* EP   = (float*)(mord + (size_t)N * 4);

    dim3 gemmGrid(1, (N + 127) / 128);
    int alphaBlocks = (N * HEADS + 255) / 256;
    int edgeBlocks  = (ET + 255) / 256;
    int scat128Blocks = (ET * 32 + 255) / 256;
    int scat40Blocks  = (ET * 40 + 255) / 256;

    // ---------- layer 1 ----------
    sgemm128<<<gemmGrid, 256, 0, stream>>>(x, W1, Hb, N, 128);
    sgemm128<<<gemmGrid, 256, 0, stream>>>(x, l1W, LIN, N, 128);
    alpha_kernel<<<alphaBlocks, 256, 0, stream>>>(Hb, a1s, a1d, asrc, adst, N, 32);
    hipMemsetAsync(mord, 0, (size_t)N * 4 * 4, stream);
    hipMemsetAsync(den, 0, (size_t)N * 4 * 4, stream);
    hipMemsetAsync(ACC, 0, (size_t)N * 128 * 4, stream);
    edge_max<<<edgeBlocks, 256, 0, stream>>>(ei, E, ET, asrc, adst, EP, mord);
    edge_sum<<<edgeBlocks, 256, 0, stream>>>(ei, E, ET, EP, mord, den);
    edge_scatter128<<<scat128Blocks, 256, 0, stream>>>(ei, E, ET, EP, Hb, ACC);
    epilogue12<<<(N * 128 + 255) / 256, 256, 0, stream>>>(ACC, den, b1, LIN, l1b, bufX, N);

    // ---------- layer 2 ----------
    sgemm128<<<gemmGrid, 256, 0, stream>>>(bufX, W2, Hb, N, 128);
    sgemm128<<<gemmGrid, 256, 0, stream>>>(bufX, l2W, LIN, N, 128);
    alpha_kernel<<<alphaBlocks, 256, 0, stream>>>(Hb, a2s, a2d, asrc, adst, N, 32);
    hipMemsetAsync(mord, 0, (size_t)N * 4 * 4, stream);
    hipMemsetAsync(den, 0, (size_t)N * 4 * 4, stream);
    hipMemsetAsync(ACC, 0, (size_t)N * 128 * 4, stream);
    edge_max<<<edgeBlocks, 256, 0, stream>>>(ei, E, ET, asrc, adst, EP, mord);
    edge_sum<<<edgeBlocks, 256, 0, stream>>>(ei, E, ET, EP, mord, den);
    edge_scatter128<<<scat128Blocks, 256, 0, stream>>>(ei, E, ET, EP, Hb, ACC);
    epilogue12<<<(N * 128 + 255) / 256, 256, 0, stream>>>(ACC, den, b2, LIN, l2b, bufX, N);

    // ---------- layer 3 ----------
    sgemm128<<<gemmGrid, 256, 0, stream>>>(bufX, W3, Hb, N, 40);
    sgemm128<<<gemmGrid, 256, 0, stream>>>(bufX, l3W, LIN, N, 10);
    alpha_kernel<<<alphaBlocks, 256, 0, stream>>>(Hb, a3s, a3d, asrc, adst, N, 10);
    hipMemsetAsync(mord, 0, (size_t)N * 4 * 4, stream);
    hipMemsetAsync(den, 0, (size_t)N * 4 * 4, stream);
    hipMemsetAsync(ACC, 0, (size_t)N * 40 * 4, stream);
    edge_max<<<edgeBlocks, 256, 0, stream>>>(ei, E, ET, asrc, adst, EP, mord);
    edge_sum<<<edgeBlocks, 256, 0, stream>>>(ei, E, ET, EP, mord, den);
    edge_scatter40<<<scat40Blocks, 256, 0, stream>>>(ei, E, ET, EP, Hb, ACC);
    epilogue3<<<(N * 10 + 255) / 256, 256, 0, stream>>>(ACC, den, b3, LIN, l3b, (float*)d_out, N);
}

// Round 2
// 725.860 us; speedup vs baseline: 5.8443x; 5.8443x over previous
//
#include <hip/hip_runtime.h>
#include <math.h>

// 3-layer GAT, fp32. N=50000, E=800000 (+N self loops), H=4 heads.
// Round 2: CSR-based per-dst-node gather; no float atomics. One wave per node
// fuses logits/max/softmax-sum/weighted-accumulate/epilogue.

#define HEADS 4

__device__ __forceinline__ float lrelu(float v) { return v > 0.f ? v : 0.2f * v; }

// ---------------- GEMM: C = A[nrows x 128] @ B[128 x M] ----------------
__global__ __launch_bounds__(256) void sgemm128(const float* __restrict__ A,
                                                const float* __restrict__ B,
                                                float* __restrict__ C,
                                                int nrows, int M) {
    __shared__ float As[8][128];
    __shared__ float Bs[8][128];
    const int tid  = threadIdx.x;
    const int row0 = blockIdx.y * 128;
    const int col0 = blockIdx.x * 128;
    const int tr   = tid >> 4;
    const int tc   = tid & 15;
    const int arow = tid >> 1;
    const int ahalf = tid & 1;

    float acc[8][8];
#pragma unroll
    for (int i = 0; i < 8; ++i)
#pragma unroll
        for (int j = 0; j < 8; ++j) acc[i][j] = 0.f;

    for (int k0 = 0; k0 < 128; k0 += 8) {
        {
            int gr = row0 + arow;
            float4 v = make_float4(0.f, 0.f, 0.f, 0.f);
            if (gr < nrows) v = *(const float4*)&A[(size_t)gr * 128 + k0 + ahalf * 4];
            As[ahalf * 4 + 0][arow] = v.x;
            As[ahalf * 4 + 1][arow] = v.y;
            As[ahalf * 4 + 2][arow] = v.z;
            As[ahalf * 4 + 3][arow] = v.w;
        }
#pragma unroll
        for (int i = tid; i < 8 * 128; i += 256) {
            int r = i >> 7, c = i & 127;
            int gc = col0 + c;
            Bs[r][c] = (gc < M) ? B[(size_t)(k0 + r) * M + gc] : 0.f;
        }
        __syncthreads();
#pragma unroll
        for (int k = 0; k < 8; ++k) {
            float a[8], b[8];
            *(float4*)&a[0] = *(const float4*)&As[k][tr * 8];
            *(float4*)&a[4] = *(const float4*)&As[k][tr * 8 + 4];
            *(float4*)&b[0] = *(const float4*)&Bs[k][tc * 8];
            *(float4*)&b[4] = *(const float4*)&Bs[k][tc * 8 + 4];
#pragma unroll
            for (int i = 0; i < 8; ++i)
#pragma unroll
                for (int j = 0; j < 8; ++j) acc[i][j] = fmaf(a[i], b[j], acc[i][j]);
        }
        __syncthreads();
    }

#pragma unroll
    for (int i = 0; i < 8; ++i) {
        int gr = row0 + tr * 8 + i;
        if (gr >= nrows) continue;
        int gc0 = col0 + tc * 8;
        if (gc0 + 7 < M) {
            *(float4*)&C[(size_t)gr * M + gc0]     = make_float4(acc[i][0], acc[i][1], acc[i][2], acc[i][3]);
            *(float4*)&C[(size_t)gr * M + gc0 + 4] = make_float4(acc[i][4], acc[i][5], acc[i][6], acc[i][7]);
        } else {
#pragma unroll
            for (int j = 0; j < 8; ++j) {
                int gc = gc0 + j;
                if (gc < M) C[(size_t)gr * M + gc] = acc[i][j];
            }
        }
    }
}

// ---------------- per-node attention coefficients ----------------
__global__ void alpha_kernel(const float* __restrict__ Hm,
                             const float* __restrict__ a_s,
                             const float* __restrict__ a_d,
                             float* __restrict__ asrc, float* __restrict__ adst,
                             int n, int C) {
    int idx = blockIdx.x * blockDim.x + threadIdx.x;
    if (idx >= n * HEADS) return;
    int node = idx >> 2, h = idx & 3;
    const float* row = Hm + (size_t)node * (HEADS * C) + h * C;
    const float* as = a_s + h * C;
    const float* ad = a_d + h * C;
    float s = 0.f, d = 0.f;
    for (int c = 0; c < C; ++c) {
        float v = row[c];
        s = fmaf(v, as[c], s);
        d = fmaf(v, ad[c], d);
    }
    asrc[idx] = s;
    adst[idx] = d;
}

// ---------------- CSR build ----------------
__global__ void deg_hist(const int* __restrict__ ei, int E, int ET, int N,
                         int* __restrict__ deg) {
    int e = blockIdx.x * blockDim.x + threadIdx.x;
    if (e >= ET) return;
    int d = (e < E) ? ei[E + e] : e - E;
    atomicAdd(&deg[d], 1);
}

__global__ void scan_block(const int* __restrict__ in, int* __restrict__ out,
                           int* __restrict__ bsum, int n) {
    __shared__ int tmp[256];
    int i = blockIdx.x * 256 + threadIdx.x;
    int v = (i < n) ? in[i] : 0;
    tmp[threadIdx.x] = v;
    __syncthreads();
    for (int d = 1; d < 256; d <<= 1) {
        int t = (threadIdx.x >= d) ? tmp[threadIdx.x - d] : 0;
        __syncthreads();
        tmp[threadIdx.x] += t;
        __syncthreads();
    }
    if (i < n) out[i] = tmp[threadIdx.x] - v;   // exclusive
    if (threadIdx.x == 255) bsum[blockIdx.x] = tmp[255];
}

__global__ void scan_bsum(int* bsum, int nb) {
    __shared__ int tmp[256];
    int v = (threadIdx.x < nb) ? bsum[threadIdx.x] : 0;
    tmp[threadIdx.x] = v;
    __syncthreads();
    for (int d = 1; d < 256; d <<= 1) {
        int t = (threadIdx.x >= d) ? tmp[threadIdx.x - d] : 0;
        __syncthreads();
        tmp[threadIdx.x] += t;
        __syncthreads();
    }
    if (threadIdx.x < nb) bsum[threadIdx.x] = tmp[threadIdx.x] - v;  // exclusive
}

__global__ void scan_add(int* out, const int* __restrict__ bsum, int n) {
    int i = blockIdx.x * 256 + threadIdx.x;
    if (i < n) out[i] += bsum[blockIdx.x];
}

__global__ void csr_fill(const int* __restrict__ ei, int E, int ET,
                         const int* __restrict__ rowptr, int* __restrict__ cur,
                         int* __restrict__ adj) {
    int e = blockIdx.x * blockDim.x + threadIdx.x;
    if (e >= ET) return;
    int s, d;
    if (e < E) { s = ei[e]; d = ei[E + e]; } else { s = d = e - E; }
    int pos = rowptr[d] + atomicAdd(&cur[d], 1);
    adj[pos] = s;
}

// ---------------- fused GAT layer (HC=128): one wave per dst node ----------------
__global__ __launch_bounds__(256) void gat_gather128(
    const int* __restrict__ rowptr, const int* __restrict__ adj, int ET,
    const float* __restrict__ Hm, const float* __restrict__ asrc,
    const float* __restrict__ adst, const float* __restrict__ bias,
    const float* __restrict__ LIN, const float* __restrict__ lbias,
    float* __restrict__ xout, int n)
{
    int node = (blockIdx.x * 256 + threadIdx.x) >> 6;
    int lane = threadIdx.x & 63;
    if (node >= n) return;
    int beg = rowptr[node];
    int end = (node + 1 < n) ? rowptr[node + 1] : ET;

    float4 ad = *(const float4*)&adst[(size_t)node * 4];

    // pass 1a: per-head max, lane-parallel over edges
    float m0 = -1e30f, m1 = -1e30f, m2 = -1e30f, m3 = -1e30f;
    for (int j = beg + lane; j < end; j += 64) {
        int s = adj[j];
        float4 av = *(const float4*)&asrc[(size_t)s * 4];
        m0 = fmaxf(m0, lrelu(av.x + ad.x));
        m1 = fmaxf(m1, lrelu(av.y + ad.y));
        m2 = fmaxf(m2, lrelu(av.z + ad.z));
        m3 = fmaxf(m3, lrelu(av.w + ad.w));
    }
#pragma unroll
    for (int off = 32; off; off >>= 1) {
        m0 = fmaxf(m0, __shfl_xor(m0, off));
        m1 = fmaxf(m1, __shfl_xor(m1, off));
        m2 = fmaxf(m2, __shfl_xor(m2, off));
        m3 = fmaxf(m3, __shfl_xor(m3, off));
    }
    // pass 1b: per-head sum of exp
    float s0 = 0.f, s1 = 0.f, s2 = 0.f, s3 = 0.f;
    for (int j = beg + lane; j < end; j += 64) {
        int s = adj[j];
        float4 av = *(const float4*)&asrc[(size_t)s * 4];
        s0 += __expf(lrelu(av.x + ad.x) - m0);
        s1 += __expf(lrelu(av.y + ad.y) - m1);
        s2 += __expf(lrelu(av.z + ad.z) - m2);
        s3 += __expf(lrelu(av.w + ad.w) - m3);
    }
#pragma unroll
    for (int off = 32; off; off >>= 1) {
        s0 += __shfl_xor(s0, off);
        s1 += __shfl_xor(s1, off);
        s2 += __shfl_xor(s2, off);
        s3 += __shfl_xor(s3, off);
    }

    // pass 2: accumulate. lane owns channels 2*lane, 2*lane+1; head = lane>>4
    int h = lane >> 4;
    float mh   = (h == 0) ? m0 : (h == 1) ? m1 : (h == 2) ? m2 : m3;
    float sh   = (h == 0) ? s0 : (h == 1) ? s1 : (h == 2) ? s2 : s3;
    float adh  = (h == 0) ? ad.x : (h == 1) ? ad.y : (h == 2) ? ad.z : ad.w;
    float invh = 1.f / (sh + 1e-16f);

    float accx = 0.f, accy = 0.f;
    for (int j = beg; j < end; ++j) {
        int s = adj[j];
        float e = lrelu(asrc[(size_t)s * 4 + h] + adh);
        float p = __expf(e - mh);
        float2 hv = *(const float2*)&Hm[(size_t)s * 128 + lane * 2];
        accx = fmaf(p, hv.x, accx);
        accy = fmaf(p, hv.y, accy);
    }
    accx *= invh;
    accy *= invh;

    int c0 = lane * 2;
    size_t o = (size_t)node * 128 + c0;
    float v0 = accx + bias[c0]     + LIN[o]     + lbias[c0];
    float v1 = accy + bias[c0 + 1] + LIN[o + 1] + lbias[c0 + 1];
    xout[o]     = v0 > 0.f ? v0 : __expf(v0) - 1.f;
    xout[o + 1] = v1 > 0.f ? v1 : __expf(v1) - 1.f;
}

// ---------------- fused GAT layer 3 (C=10, mean over heads) ----------------
__global__ __launch_bounds__(256) void gat_gather40(
    const int* __restrict__ rowptr, const int* __restrict__ adj, int ET,
    const float* __restrict__ Hm, const float* __restrict__ asrc,
    const float* __restrict__ adst, const float* __restrict__ bias,
    const float* __restrict__ LIN, const float* __restrict__ lbias,
    float* __restrict__ out, int n)
{
    int node = (blockIdx.x * 256 + threadIdx.x) >> 6;
    int lane = threadIdx.x & 63;
    if (node >= n) return;
    int beg = rowptr[node];
    int end = (node + 1 < n) ? rowptr[node + 1] : ET;

    float4 ad = *(const float4*)&adst[(size_t)node * 4];

    float m0 = -1e30f, m1 = -1e30f, m2 = -1e30f, m3 = -1e30f;
    for (int j = beg + lane; j < end; j += 64) {
        int s = adj[j];
        float4 av = *(const float4*)&asrc[(size_t)s * 4];
        m0 = fmaxf(m0, lrelu(av.x + ad.x));
        m1 = fmaxf(m1, lrelu(av.y + ad.y));
        m2 = fmaxf(m2, lrelu(av.z + ad.z));
        m3 = fmaxf(m3, lrelu(av.w + ad.w));
    }
#pragma unroll
    for (int off = 32; off; off >>= 1) {
        m0 = fmaxf(m0, __shfl_xor(m0, off));
        m1 = fmaxf(m1, __shfl_xor(m1, off));
        m2 = fmaxf(m2, __shfl_xor(m2, off));
        m3 = fmaxf(m3, __shfl_xor(m3, off));
    }
    float s0 = 0.f, s1 = 0.f, s2 = 0.f, s3 = 0.f;
    for (int j = beg + lane; j < end; j += 64) {
        int s = adj[j];
        float4 av = *(const float4*)&asrc[(size_t)s * 4];
        s0 += __expf(lrelu(av.x + ad.x) - m0);
        s1 += __expf(lrelu(av.y + ad.y) - m1);
        s2 += __expf(lrelu(av.z + ad.z) - m2);
        s3 += __expf(lrelu(av.w + ad.w) - m3);
    }
#pragma unroll
    for (int off = 32; off; off >>= 1) {
        s0 += __shfl_xor(s0, off);
        s1 += __shfl_xor(s1, off);
        s2 += __shfl_xor(s2, off);
        s3 += __shfl_xor(s3, off);
    }

    // lanes 0..39 own channel c=lane (head = c/10)
    int c = lane;
    int h = c / 10;           // valid for c<40
    float mh, sh, adh;
    if (h == 0)      { mh = m0; sh = s0; adh = ad.x; }
    else if (h == 1) { mh = m1; sh = s1; adh = ad.y; }
    else if (h == 2) { mh = m2; sh = s2; adh = ad.z; }
    else             { mh = m3; sh = s3; adh = ad.w; }
    float invh = 1.f / (sh + 1e-16f);

    float acc = 0.f;
    if (c < 40) {
        for (int j = beg; j < end; ++j) {
            int s = adj[j];
            float e = lrelu(asrc[(size_t)s * 4 + h] + adh);
            float p = __expf(e - mh);
            acc = fmaf(p, Hm[(size_t)s * 40 + c], acc);
        }
        acc *= invh;
    }
    // mean over heads: channel cc = c (<10) gathers lanes c, c+10, c+20, c+30
    float a1 = __shfl(acc, lane + 10);
    float a2 = __shfl(acc, lane + 20);
    float a3 = __shfl(acc, lane + 30);
    if (c < 10) {
        size_t o = (size_t)node * 10 + c;
        out[o] = 0.25f * (acc + a1 + a2 + a3) + bias[c] + LIN[o] + lbias[c];
    }
}

extern "C" void kernel_launch(void* const* d_in, const int* in_sizes, int n_in,
                              void* d_out, int out_size, void* d_ws, size_t ws_size,
                              hipStream_t stream) {
    const float* x   = (const float*)d_in[0];
    const int*   ei  = (const int*)d_in[1];
    const float* W1  = (const float*)d_in[2];
    const float* a1s = (const float*)d_in[3];
    const float* a1d = (const float*)d_in[4];
    const float* b1  = (const float*)d_in[5];
    const float* l1W = (const float*)d_in[6];
    const float* l1b = (const float*)d_in[7];
    const float* W2  = (const float*)d_in[8];
    const float* a2s = (const float*)d_in[9];
    const float* a2d = (const float*)d_in[10];
    const float* b2  = (const float*)d_in[11];
    const float* l2W = (const float*)d_in[12];
    const float* l2b = (const float*)d_in[13];
    const float* W3  = (const float*)d_in[14];
    const float* a3s = (const float*)d_in[15];
    const float* a3d = (const float*)d_in[16];
    const float* b3  = (const float*)d_in[17];
    const float* l3W = (const float*)d_in[18];
    const float* l3b = (const float*)d_in[19];

    const int N  = in_sizes[0] / 128;
    const int E  = in_sizes[1] / 2;
    const int ET = E + N;

    float* bufX = (float*)d_ws;
    float* Hb   = bufX + (size_t)N * 128;
    float* LIN  = Hb + (size_t)N * 128;
    float* asrc = LIN + (size_t)N * 128;
    float* adst = asrc + (size_t)N * 4;
    int* deg    = (int*)(adst + (size_t)N * 4);
    int* rowptr = deg + N;
    int* cur    = rowptr + N;
    int* bsum   = cur + N;
    int* adj    = bsum + 256;

    const int nScanBlocks = (N + 255) / 256;
    int alphaBlocks = (N * HEADS + 255) / 256;
    int edgeBlocks  = (ET + 255) / 256;
    int waveBlocks  = (N * 64 + 255) / 256;   // one wave per node
    dim3 gemmGrid(1, (N + 127) / 128);

    // ---------- CSR build (shared by all 3 layers) ----------
    hipMemsetAsync(deg, 0, (size_t)N * 4, stream);
    hipMemsetAsync(cur, 0, (size_t)N * 4, stream);
    deg_hist<<<edgeBlocks, 256, 0, stream>>>(ei, E, ET, N, deg);
    scan_block<<<nScanBlocks, 256, 0, stream>>>(deg, rowptr, bsum, N);
    scan_bsum<<<1, 256, 0, stream>>>(bsum, nScanBlocks);
    scan_add<<<nScanBlocks, 256, 0, stream>>>(rowptr, bsum, N);
    csr_fill<<<edgeBlocks, 256, 0, stream>>>(ei, E, ET, rowptr, cur, adj);

    // ---------- layer 1 ----------
    sgemm128<<<gemmGrid, 256, 0, stream>>>(x, W1, Hb, N, 128);
    sgemm128<<<gemmGrid, 256, 0, stream>>>(x, l1W, LIN, N, 128);
    alpha_kernel<<<alphaBlocks, 256, 0, stream>>>(Hb, a1s, a1d, asrc, adst, N, 32);
    gat_gather128<<<waveBlocks, 256, 0, stream>>>(rowptr, adj, ET, Hb, asrc, adst,
                                                  b1, LIN, l1b, bufX, N);

    // ---------- layer 2 ----------
    sgemm128<<<gemmGrid, 256, 0, stream>>>(bufX, W2, Hb, N, 128);
    sgemm128<<<gemmGrid, 256, 0, stream>>>(bufX, l2W, LIN, N, 128);
    alpha_kernel<<<alphaBlocks, 256, 0, stream>>>(Hb, a2s, a2d, asrc, adst, N, 32);
    gat_gather128<<<waveBlocks, 256, 0, stream>>>(rowptr, adj, ET, Hb, asrc, adst,
                                                  b2, LIN, l2b, bufX, N);

    // ---------- layer 3 ----------
    sgemm128<<<gemmGrid, 256, 0, stream>>>(bufX, W3, Hb, N, 40);
    sgemm128<<<gemmGrid, 256, 0, stream>>>(bufX, l3W, LIN, N, 10);
    alpha_kernel<<<alphaBlocks, 256, 0, stream>>>(Hb, a3s, a3d, asrc, adst, N, 10);
    gat_gather40<<<waveBlocks, 256, 0, stream>>>(rowptr, adj, ET, Hb, asrc, adst,
                                                 b3, LIN, l3b, (float*)d_out, N);
}

// Round 3
// 491.994 us; speedup vs baseline: 8.6224x; 1.4753x over previous
//
#include <hip/hip_runtime.h>
#include <math.h>

// 3-layer GAT. Round 3: bf16 feature path + MFMA GEMMs (fused h|lin), CSR gather
// with online softmax and 2-edge-parallel weighted accumulate. No float atomics.

#define HEADS 4

typedef __attribute__((ext_vector_type(8))) short short8v;   // 8 bf16 (4 VGPRs)
typedef __attribute__((ext_vector_type(4))) float float4v;   // 4 fp32 acc

__device__ __forceinline__ float lrelu(float v) { return v > 0.f ? v : 0.2f * v; }

__device__ __forceinline__ unsigned short f2bf(float f) {
    unsigned u = __float_as_uint(f);
    unsigned r = u + 0x7FFFu + ((u >> 16) & 1u);   // RNE
    return (unsigned short)(r >> 16);
}
__device__ __forceinline__ float bf2f(unsigned short u) {
    return __uint_as_float(((unsigned)u) << 16);
}

// ---------------- pack / cast kernels ----------------
__global__ void castX(const float* __restrict__ x, unsigned short* __restrict__ xb, int n4) {
    int i = blockIdx.x * blockDim.x + threadIdx.x;
    if (i >= n4) return;
    float4 v = *(const float4*)&x[(size_t)i * 4];
    ushort4 o;
    o.x = f2bf(v.x); o.y = f2bf(v.y); o.z = f2bf(v.z); o.w = f2bf(v.w);
    *(ushort4*)&xb[(size_t)i * 4] = o;
}

// BT[m][k] = W[k][m] (m<128) or LW[k][m-128], bf16. M=256, K=128.
__global__ void packB12(const float* __restrict__ W, const float* __restrict__ LW,
                        unsigned short* __restrict__ BT) {
    int i = blockIdx.x * blockDim.x + threadIdx.x;
    if (i >= 256 * 128) return;
    int m = i >> 7, k = i & 127;
    float v = (m < 128) ? W[(size_t)k * 128 + m] : LW[(size_t)k * 128 + (m - 128)];
    BT[i] = f2bf(v);
}

// BT3[m][k]: m<40 -> W3[k][m]; 40<=m<50 -> LW3[k][m-40]; else 0. M=64, K=128.
__global__ void packB3(const float* __restrict__ W3, const float* __restrict__ LW3,
                       unsigned short* __restrict__ BT) {
    int i = blockIdx.x * blockDim.x + threadIdx.x;
    if (i >= 64 * 128) return;
    int m = i >> 7, k = i & 127;
    float v = 0.f;
    if (m < 40)      v = W3[(size_t)k * 40 + m];
    else if (m < 50) v = LW3[(size_t)k * 10 + (m - 40)];
    BT[i] = f2bf(v);
}

// ---------------- MFMA GEMM: C[n][M] = A[n][128] @ BT[M][128]^T, all bf16 ----------------
// block = 256 threads = 4 waves; block tile 64 rows x 64 cols; K=128 in 4 steps.
__global__ __launch_bounds__(256) void mfma_gemm(const unsigned short* __restrict__ A,
                                                 const unsigned short* __restrict__ BT,
                                                 unsigned short* __restrict__ C,
                                                 int nrows, int M) {
    const int wave = threadIdx.x >> 6;
    const int lane = threadIdx.x & 63;
    const int row0 = blockIdx.y * 64 + wave * 16;
    const int col0 = blockIdx.x * 64;
    const int lrow = lane & 15;
    const int kgrp = lane >> 4;              // 0..3, covers k-offsets kgrp*8..+7

    float4v acc0 = {0.f, 0.f, 0.f, 0.f};
    float4v acc1 = {0.f, 0.f, 0.f, 0.f};
    float4v acc2 = {0.f, 0.f, 0.f, 0.f};
    float4v acc3 = {0.f, 0.f, 0.f, 0.f};

    int arow = row0 + lrow;
    if (arow >= nrows) arow = nrows - 1;     // clamp (rows independent; guarded at store)
    const unsigned short* Ap = A + (size_t)arow * 128 + kgrp * 8;
    const unsigned short* Bp = BT + (size_t)(col0 + lrow) * 128 + kgrp * 8;

#pragma unroll
    for (int t = 0; t < 4; ++t) {
        short8v a = *(const short8v*)(Ap + t * 32);
        short8v b0 = *(const short8v*)(Bp + t * 32);
        short8v b1 = *(const short8v*)(Bp + 16 * 128 + t * 32);
        short8v b2 = *(const short8v*)(Bp + 32 * 128 + t * 32);
        short8v b3 = *(const short8v*)(Bp + 48 * 128 + t * 32);
        acc0 = __builtin_amdgcn_mfma_f32_16x16x32_bf16(a, b0, acc0, 0, 0, 0);
        acc1 = __builtin_amdgcn_mfma_f32_16x16x32_bf16(a, b1, acc1, 0, 0, 0);
        acc2 = __builtin_amdgcn_mfma_f32_16x16x32_bf16(a, b2, acc2, 0, 0, 0);
        acc3 = __builtin_amdgcn_mfma_f32_16x16x32_bf16(a, b3, acc3, 0, 0, 0);
    }

    // C/D layout: col = lane&15, row = (lane>>4)*4 + reg
#pragma unroll
    for (int r = 0; r < 4; ++r) {
        int row = row0 + kgrp * 4 + r;
        if (row >= nrows) continue;
        size_t base = (size_t)row * M + col0 + lrow;
        C[base]      = f2bf(acc0[r]);
        C[base + 16] = f2bf(acc1[r]);
        C[base + 32] = f2bf(acc2[r]);
        C[base + 48] = f2bf(acc3[r]);
    }
}

// ---------------- per-node attention coefficients (bf16 h) ----------------
__global__ void alpha_kernel(const unsigned short* __restrict__ Hm,
                             const float* __restrict__ a_s,
                             const float* __restrict__ a_d,
                             float* __restrict__ asrc, float* __restrict__ adst,
                             int n, int C, int rowStride) {
    int idx = blockIdx.x * blockDim.x + threadIdx.x;
    if (idx >= n * HEADS) return;
    int node = idx >> 2, h = idx & 3;
    const unsigned short* row = Hm + (size_t)node * rowStride + h * C;
    const float* as = a_s + h * C;
    const float* ad = a_d + h * C;
    float s = 0.f, d = 0.f;
    for (int c = 0; c < C; ++c) {
        float v = bf2f(row[c]);
        s = fmaf(v, as[c], s);
        d = fmaf(v, ad[c], d);
    }
    asrc[idx] = s;
    adst[idx] = d;
}

// ---------------- CSR build ----------------
__global__ void deg_hist(const int* __restrict__ ei, int E, int ET, int N,
                         int* __restrict__ deg) {
    int e = blockIdx.x * blockDim.x + threadIdx.x;
    if (e >= ET) return;
    int d = (e < E) ? ei[E + e] : e - E;
    atomicAdd(&deg[d], 1);
}

__global__ void scan_block(const int* __restrict__ in, int* __restrict__ out,
                           int* __restrict__ bsum, int n) {
    __shared__ int tmp[256];
    int i = blockIdx.x * 256 + threadIdx.x;
    int v = (i < n) ? in[i] : 0;
    tmp[threadIdx.x] = v;
    __syncthreads();
    for (int d = 1; d < 256; d <<= 1) {
        int t = (threadIdx.x >= d) ? tmp[threadIdx.x - d] : 0;
        __syncthreads();
        tmp[threadIdx.x] += t;
        __syncthreads();
    }
    if (i < n) out[i] = tmp[threadIdx.x] - v;   // exclusive
    if (threadIdx.x == 255) bsum[blockIdx.x] = tmp[255];
}

__global__ void scan_bsum(int* bsum, int nb) {
    __shared__ int tmp[256];
    int v = (threadIdx.x < nb) ? bsum[threadIdx.x] : 0;
    tmp[threadIdx.x] = v;
    __syncthreads();
    for (int d = 1; d < 256; d <<= 1) {
        int t = (threadIdx.x >= d) ? tmp[threadIdx.x - d] : 0;
        __syncthreads();
        tmp[threadIdx.x] += t;
        __syncthreads();
    }
    if (threadIdx.x < nb) bsum[threadIdx.x] = tmp[threadIdx.x] - v;  // exclusive
}

__global__ void scan_add(int* out, const int* __restrict__ bsum, int n) {
    int i = blockIdx.x * 256 + threadIdx.x;
    if (i < n) out[i] += bsum[blockIdx.x];
}

__global__ void csr_fill(const int* __restrict__ ei, int E, int ET,
                         const int* __restrict__ rowptr, int* __restrict__ cur,
                         int* __restrict__ adj) {
    int e = blockIdx.x * blockDim.x + threadIdx.x;
    if (e >= ET) return;
    int s, d;
    if (e < E) { s = ei[e]; d = ei[E + e]; } else { s = d = e - E; }
    int pos = rowptr[d] + atomicAdd(&cur[d], 1);
    adj[pos] = s;
}

// ---------------- fused GAT layer (HC=128): one wave per dst node ----------------
// Hb row (stride 256 bf16): cols 0..127 = h, cols 128..255 = lin. Output bf16 [N][128].
__global__ __launch_bounds__(256) void gat_gather128(
    const int* __restrict__ rowptr, const int* __restrict__ adj, int ET,
    const unsigned short* __restrict__ Hb, const float* __restrict__ asrc,
    const float* __restrict__ adst, const float* __restrict__ bias,
    const float* __restrict__ lbias, unsigned short* __restrict__ xout, int n)
{
    int node = (blockIdx.x * 256 + threadIdx.x) >> 6;
    int lane = threadIdx.x & 63;
    if (node >= n) return;
    int beg = rowptr[node];
    int end = (node + 1 < n) ? rowptr[node + 1] : ET;

    float4 ad = *(const float4*)&adst[(size_t)node * 4];

    // pass 1: online softmax stats per head (merged max+sum)
    float m0 = -1e30f, m1 = -1e30f, m2 = -1e30f, m3 = -1e30f;
    float s0 = 0.f, s1 = 0.f, s2 = 0.f, s3 = 0.f;
    for (int j = beg + lane; j < end; j += 64) {
        int s = adj[j];
        float4 av = *(const float4*)&asrc[(size_t)s * 4];
        float v;
        v = lrelu(av.x + ad.x);
        if (v > m0) { s0 = s0 * __expf(m0 - v) + 1.f; m0 = v; } else s0 += __expf(v - m0);
        v = lrelu(av.y + ad.y);
        if (v > m1) { s1 = s1 * __expf(m1 - v) + 1.f; m1 = v; } else s1 += __expf(v - m1);
        v = lrelu(av.z + ad.z);
        if (v > m2) { s2 = s2 * __expf(m2 - v) + 1.f; m2 = v; } else s2 += __expf(v - m2);
        v = lrelu(av.w + ad.w);
        if (v > m3) { s3 = s3 * __expf(m3 - v) + 1.f; m3 = v; } else s3 += __expf(v - m3);
    }
#pragma unroll
    for (int off = 32; off; off >>= 1) {
        float om, os, nm;
        om = __shfl_xor(m0, off); os = __shfl_xor(s0, off);
        nm = fmaxf(m0, om); s0 = s0 * __expf(m0 - nm) + os * __expf(om - nm); m0 = nm;
        om = __shfl_xor(m1, off); os = __shfl_xor(s1, off);
        nm = fmaxf(m1, om); s1 = s1 * __expf(m1 - nm) + os * __expf(om - nm); m1 = nm;
        om = __shfl_xor(m2, off); os = __shfl_xor(s2, off);
        nm = fmaxf(m2, om); s2 = s2 * __expf(m2 - nm) + os * __expf(om - nm); m2 = nm;
        om = __shfl_xor(m3, off); os = __shfl_xor(s3, off);
        nm = fmaxf(m3, om); s3 = s3 * __expf(m3 - nm) + os * __expf(om - nm); m3 = nm;
    }

    // pass 2: 2 edges in parallel (ep), 32 sub-lanes x 4 bf16 channels each
    int sub = lane & 31, ep = lane >> 5;
    int c0 = sub * 4;
    int h = sub >> 3;
    float mh  = (h == 0) ? m0 : (h == 1) ? m1 : (h == 2) ? m2 : m3;
    float sh  = (h == 0) ? s0 : (h == 1) ? s1 : (h == 2) ? s2 : s3;
    float adh = (h == 0) ? ad.x : (h == 1) ? ad.y : (h == 2) ? ad.z : ad.w;
    float inv = 1.f / (sh + 1e-16f);

    float a0 = 0.f, a1 = 0.f, a2 = 0.f, a3 = 0.f;
    for (int j = beg + ep; j < end; j += 2) {
        int s = adj[j];
        float e = lrelu(asrc[(size_t)s * 4 + h] + adh);
        float p = __expf(e - mh);
        ushort4 hv = *(const ushort4*)&Hb[(size_t)s * 256 + c0];
        a0 = fmaf(p, bf2f(hv.x), a0);
        a1 = fmaf(p, bf2f(hv.y), a1);
        a2 = fmaf(p, bf2f(hv.z), a2);
        a3 = fmaf(p, bf2f(hv.w), a3);
    }
    a0 += __shfl_xor(a0, 32);
    a1 += __shfl_xor(a1, 32);
    a2 += __shfl_xor(a2, 32);
    a3 += __shfl_xor(a3, 32);

    if (ep == 0) {
        ushort4 lv = *(const ushort4*)&Hb[(size_t)node * 256 + 128 + c0];
        float v0 = a0 * inv + bias[c0]     + bf2f(lv.x) + lbias[c0];
        float v1 = a1 * inv + bias[c0 + 1] + bf2f(lv.y) + lbias[c0 + 1];
        float v2 = a2 * inv + bias[c0 + 2] + bf2f(lv.z) + lbias[c0 + 2];
        float v3 = a3 * inv + bias[c0 + 3] + bf2f(lv.w) + lbias[c0 + 3];
        v0 = v0 > 0.f ? v0 : __expf(v0) - 1.f;
        v1 = v1 > 0.f ? v1 : __expf(v1) - 1.f;
        v2 = v2 > 0.f ? v2 : __expf(v2) - 1.f;
        v3 = v3 > 0.f ? v3 : __expf(v3) - 1.f;
        ushort4 w;
        w.x = f2bf(v0); w.y = f2bf(v1); w.z = f2bf(v2); w.w = f2bf(v3);
        *(ushort4*)&xout[(size_t)node * 128 + c0] = w;
    }
}

// ---------------- fused GAT layer 3 (C=10, mean over heads) ----------------
// Hb3 row (stride 64 bf16): cols 0..39 = h (4 heads x 10), cols 40..49 = lin.
__global__ __launch_bounds__(256) void gat_gather40(
    const int* __restrict__ rowptr, const int* __restrict__ adj, int ET,
    const unsigned short* __restrict__ Hb3, const float* __restrict__ asrc,
    const float* __restrict__ adst, const float* __restrict__ bias,
    const float* __restrict__ lbias, float* __restrict__ out, int n)
{
    int node = (blockIdx.x * 256 + threadIdx.x) >> 6;
    int lane = threadIdx.x & 63;
    if (node >= n) return;
    int beg = rowptr[node];
    int end = (node + 1 < n) ? rowptr[node + 1] : ET;

    float4 ad = *(const float4*)&adst[(size_t)node * 4];

    float m0 = -1e30f, m1 = -1e30f, m2 = -1e30f, m3 = -1e30f;
    float s0 = 0.f, s1 = 0.f, s2 = 0.f, s3 = 0.f;
    for (int j = beg + lane; j < end; j += 64) {
        int s = adj[j];
        float4 av = *(const float4*)&asrc[(size_t)s * 4];
        float v;
        v = lrelu(av.x + ad.x);
        if (v > m0) { s0 = s0 * __expf(m0 - v) + 1.f; m0 = v; } else s0 += __expf(v - m0);
        v = lrelu(av.y + ad.y);
        if (v > m1) { s1 = s1 * __expf(m1 - v) + 1.f; m1 = v; } else s1 += __expf(v - m1);
        v = lrelu(av.z + ad.z);
        if (v > m2) { s2 = s2 * __expf(m2 - v) + 1.f; m2 = v; } else s2 += __expf(v - m2);
        v = lrelu(av.w + ad.w);
        if (v > m3) { s3 = s3 * __expf(m3 - v) + 1.f; m3 = v; } else s3 += __expf(v - m3);
    }
#pragma unroll
    for (int off = 32; off; off >>= 1) {
        float om, os, nm;
        om = __shfl_xor(m0, off); os = __shfl_xor(s0, off);
        nm = fmaxf(m0, om); s0 = s0 * __expf(m0 - nm) + os * __expf(om - nm); m0 = nm;
        om = __shfl_xor(m1, off); os = __shfl_xor(s1, off);
        nm = fmaxf(m1, om); s1 = s1 * __expf(m1 - nm) + os * __expf(om - nm); m1 = nm;
        om = __shfl_xor(m2, off); os = __shfl_xor(s2, off);
        nm = fmaxf(m2, om); s2 = s2 * __expf(m2 - nm) + os * __expf(om - nm); m2 = nm;
        om = __shfl_xor(m3, off); os = __shfl_xor(s3, off);
        nm = fmaxf(m3, om); s3 = s3 * __expf(m3 - nm) + os * __expf(om - nm); m3 = nm;
    }

    int c = lane;
    int h = (c < 40) ? (c / 10) : 0;
    float mh, sh, adh;
    if (h == 0)      { mh = m0; sh = s0; adh = ad.x; }
    else if (h == 1) { mh = m1; sh = s1; adh = ad.y; }
    else if (h == 2) { mh = m2; sh = s2; adh = ad.z; }
    else             { mh = m3; sh = s3; adh = ad.w; }
    float inv = 1.f / (sh + 1e-16f);

    float acc = 0.f;
    if (c < 40) {
        for (int j = beg; j < end; ++j) {
            int s = adj[j];
            float e = lrelu(asrc[(size_t)s * 4 + h] + adh);
            float p = __expf(e - mh);
            acc = fmaf(p, bf2f(Hb3[(size_t)s * 64 + c]), acc);
        }
        acc *= inv;
    }
    float g1 = __shfl(acc, lane + 10);
    float g2 = __shfl(acc, lane + 20);
    float g3 = __shfl(acc, lane + 30);
    if (c < 10) {
        size_t o = (size_t)node * 10 + c;
        float lin = bf2f(Hb3[(size_t)node * 64 + 40 + c]);
        out[o] = 0.25f * (acc + g1 + g2 + g3) + bias[c] + lin + lbias[c];
    }
}

extern "C" void kernel_launch(void* const* d_in, const int* in_sizes, int n_in,
                              void* d_out, int out_size, void* d_ws, size_t ws_size,
                              hipStream_t stream) {
    const float* x   = (const float*)d_in[0];
    const int*   ei  = (const int*)d_in[1];
    const float* W1  = (const float*)d_in[2];
    const float* a1s = (const float*)d_in[3];
    const float* a1d = (const float*)d_in[4];
    const float* b1  = (const float*)d_in[5];
    const float* l1W = (const float*)d_in[6];
    const float* l1b = (const float*)d_in[7];
    const float* W2  = (const float*)d_in[8];
    const float* a2s = (const float*)d_in[9];
    const float* a2d = (const float*)d_in[10];
    const float* b2  = (const float*)d_in[11];
    const float* l2W = (const float*)d_in[12];
    const float* l2b = (const float*)d_in[13];
    const float* W3  = (const float*)d_in[14];
    const float* a3s = (const float*)d_in[15];
    const float* a3d = (const float*)d_in[16];
    const float* b3  = (const float*)d_in[17];
    const float* l3W = (const float*)d_in[18];
    const float* l3b = (const float*)d_in[19];

    const int N  = in_sizes[0] / 128;
    const int E  = in_sizes[1] / 2;
    const int ET = E + N;

    unsigned short* Xb = (unsigned short*)d_ws;           // N*128 bf16
    unsigned short* Hb = Xb + (size_t)N * 128;            // N*256 bf16
    unsigned short* BT = Hb + (size_t)N * 256;            // 256*128 bf16
    float* asrc = (float*)(BT + 256 * 128);               // N*4
    float* adst = asrc + (size_t)N * 4;                   // N*4
    int* deg    = (int*)(adst + (size_t)N * 4);
    int* rowptr = deg + N;
    int* cur    = rowptr + N;
    int* bsum   = cur + N;
    int* adj    = bsum + 256;                             // ET ints

    const int nScanBlocks = (N + 255) / 256;
    int alphaBlocks = (N * HEADS + 255) / 256;
    int edgeBlocks  = (ET + 255) / 256;
    int waveBlocks  = (N * 64 + 255) / 256;
    int rowBlocks   = (N + 63) / 64;

    // ---------- CSR build (shared by all 3 layers) ----------
    hipMemsetAsync(deg, 0, (size_t)N * 4, stream);
    hipMemsetAsync(cur, 0, (size_t)N * 4, stream);
    deg_hist<<<edgeBlocks, 256, 0, stream>>>(ei, E, ET, N, deg);
    scan_block<<<nScanBlocks, 256, 0, stream>>>(deg, rowptr, bsum, N);
    scan_bsum<<<1, 256, 0, stream>>>(bsum, nScanBlocks);
    scan_add<<<nScanBlocks, 256, 0, stream>>>(rowptr, bsum, N);
    csr_fill<<<edgeBlocks, 256, 0, stream>>>(ei, E, ET, rowptr, cur, adj);

    castX<<<(N * 32 + 255) / 256, 256, 0, stream>>>(x, Xb, N * 32);

    // ---------- layer 1 ----------
    packB12<<<(256 * 128 + 255) / 256, 256, 0, stream>>>(W1, l1W, BT);
    mfma_gemm<<<dim3(4, rowBlocks), 256, 0, stream>>>(Xb, BT, Hb, N, 256);
    alpha_kernel<<<alphaBlocks, 256, 0, stream>>>(Hb, a1s, a1d, asrc, adst, N, 32, 256);
    gat_gather128<<<waveBlocks, 256, 0, stream>>>(rowptr, adj, ET, Hb, asrc, adst,
                                                  b1, l1b, Xb, N);

    // ---------- layer 2 ----------
    packB12<<<(256 * 128 + 255) / 256, 256, 0, stream>>>(W2, l2W, BT);
    mfma_gemm<<<dim3(4, rowBlocks), 256, 0, stream>>>(Xb, BT, Hb, N, 256);
    alpha_kernel<<<alphaBlocks, 256, 0, stream>>>(Hb, a2s, a2d, asrc, adst, N, 32, 256);
    gat_gather128<<<waveBlocks, 256, 0, stream>>>(rowptr, adj, ET, Hb, asrc, adst,
                                                  b2, l2b, Xb, N);

    // ---------- layer 3 ----------
    packB3<<<(64 * 128 + 255) / 256, 256, 0, stream>>>(W3, l3W, BT);
    mfma_gemm<<<dim3(1, rowBlocks), 256, 0, stream>>>(Xb, BT, Hb, N, 64);
    alpha_kernel<<<alphaBlocks, 256, 0, stream>>>(Hb, a3s, a3d, asrc, adst, N, 10, 64);
    gat_gather40<<<waveBlocks, 256, 0, stream>>>(rowptr, adj, ET, Hb, asrc, adst,
                                                 b3, l3b, (float*)d_out, N);
}

// Round 4
// 383.860 us; speedup vs baseline: 11.0513x; 1.2817x over previous
//
#include <hip/hip_runtime.h>
#include <math.h>

// 3-layer GAT. Round 4: per-edge softmax numerators precomputed edge-parallel
// (no max-shift; magnitudes are safe), single fused gather pass per layer that
// accumulates both sum(p) and sum(p*H). bf16 feature path + MFMA GEMMs.

#define HEADS 4

typedef __attribute__((ext_vector_type(8))) short short8v;   // 8 bf16
typedef __attribute__((ext_vector_type(4))) float float4v;   // 4 fp32 acc

__device__ __forceinline__ float lrelu(float v) { return v > 0.f ? v : 0.2f * v; }

__device__ __forceinline__ unsigned short f2bf(float f) {
    unsigned u = __float_as_uint(f);
    unsigned r = u + 0x7FFFu + ((u >> 16) & 1u);   // RNE
    return (unsigned short)(r >> 16);
}
__device__ __forceinline__ float bf2f(unsigned short u) {
    return __uint_as_float(((unsigned)u) << 16);
}

// ---------------- pack / cast kernels ----------------
__global__ void castX(const float* __restrict__ x, unsigned short* __restrict__ xb, int n4) {
    int i = blockIdx.x * blockDim.x + threadIdx.x;
    if (i >= n4) return;
    float4 v = *(const float4*)&x[(size_t)i * 4];
    ushort4 o;
    o.x = f2bf(v.x); o.y = f2bf(v.y); o.z = f2bf(v.z); o.w = f2bf(v.w);
    *(ushort4*)&xb[(size_t)i * 4] = o;
}

__global__ void packB12(const float* __restrict__ W, const float* __restrict__ LW,
                        unsigned short* __restrict__ BT) {
    int i = blockIdx.x * blockDim.x + threadIdx.x;
    if (i >= 256 * 128) return;
    int m = i >> 7, k = i & 127;
    float v = (m < 128) ? W[(size_t)k * 128 + m] : LW[(size_t)k * 128 + (m - 128)];
    BT[i] = f2bf(v);
}

__global__ void packB3(const float* __restrict__ W3, const float* __restrict__ LW3,
                       unsigned short* __restrict__ BT) {
    int i = blockIdx.x * blockDim.x + threadIdx.x;
    if (i >= 64 * 128) return;
    int m = i >> 7, k = i & 127;
    float v = 0.f;
    if (m < 40)      v = W3[(size_t)k * 40 + m];
    else if (m < 50) v = LW3[(size_t)k * 10 + (m - 40)];
    BT[i] = f2bf(v);
}

// ---------------- MFMA GEMM: C[n][M] = A[n][128] @ BT[M][128]^T, bf16 ----------------
__global__ __launch_bounds__(256) void mfma_gemm(const unsigned short* __restrict__ A,
                                                 const unsigned short* __restrict__ BT,
                                                 unsigned short* __restrict__ C,
                                                 int nrows, int M) {
    const int wave = threadIdx.x >> 6;
    const int lane = threadIdx.x & 63;
    const int row0 = blockIdx.y * 64 + wave * 16;
    const int col0 = blockIdx.x * 64;
    const int lrow = lane & 15;
    const int kgrp = lane >> 4;

    float4v acc0 = {0.f, 0.f, 0.f, 0.f};
    float4v acc1 = {0.f, 0.f, 0.f, 0.f};
    float4v acc2 = {0.f, 0.f, 0.f, 0.f};
    float4v acc3 = {0.f, 0.f, 0.f, 0.f};

    int arow = row0 + lrow;
    if (arow >= nrows) arow = nrows - 1;
    const unsigned short* Ap = A + (size_t)arow * 128 + kgrp * 8;
    const unsigned short* Bp = BT + (size_t)(col0 + lrow) * 128 + kgrp * 8;

#pragma unroll
    for (int t = 0; t < 4; ++t) {
        short8v a = *(const short8v*)(Ap + t * 32);
        short8v b0 = *(const short8v*)(Bp + t * 32);
        short8v b1 = *(const short8v*)(Bp + 16 * 128 + t * 32);
        short8v b2 = *(const short8v*)(Bp + 32 * 128 + t * 32);
        short8v b3 = *(const short8v*)(Bp + 48 * 128 + t * 32);
        acc0 = __builtin_amdgcn_mfma_f32_16x16x32_bf16(a, b0, acc0, 0, 0, 0);
        acc1 = __builtin_amdgcn_mfma_f32_16x16x32_bf16(a, b1, acc1, 0, 0, 0);
        acc2 = __builtin_amdgcn_mfma_f32_16x16x32_bf16(a, b2, acc2, 0, 0, 0);
        acc3 = __builtin_amdgcn_mfma_f32_16x16x32_bf16(a, b3, acc3, 0, 0, 0);
    }

#pragma unroll
    for (int r = 0; r < 4; ++r) {
        int row = row0 + kgrp * 4 + r;
        if (row >= nrows) continue;
        size_t base = (size_t)row * M + col0 + lrow;
        C[base]      = f2bf(acc0[r]);
        C[base + 16] = f2bf(acc1[r]);
        C[base + 32] = f2bf(acc2[r]);
        C[base + 48] = f2bf(acc3[r]);
    }
}

// ---------------- attention coefficients ----------------
// C=32, rowStride=256, vectorized ushort8 loads
__global__ void alpha32(const unsigned short* __restrict__ Hm,
                        const float* __restrict__ a_s, const float* __restrict__ a_d,
                        float* __restrict__ asrc, float* __restrict__ adst, int n) {
    int idx = blockIdx.x * blockDim.x + threadIdx.x;
    if (idx >= n * HEADS) return;
    int node = idx >> 2, h = idx & 3;
    const unsigned short* row = Hm + (size_t)node * 256 + h * 32;
    const float* as = a_s + h * 32;
    const float* ad = a_d + h * 32;
    float s = 0.f, d = 0.f;
#pragma unroll
    for (int ch = 0; ch < 4; ++ch) {
        short8v v = *(const short8v*)(row + ch * 8);
#pragma unroll
        for (int k = 0; k < 8; ++k) {
            float f = bf2f((unsigned short)v[k]);
            s = fmaf(f, as[ch * 8 + k], s);
            d = fmaf(f, ad[ch * 8 + k], d);
        }
    }
    asrc[idx] = s;
    adst[idx] = d;
}

// generic (layer 3: C=10, rowStride=64)
__global__ void alpha_gen(const unsigned short* __restrict__ Hm,
                          const float* __restrict__ a_s, const float* __restrict__ a_d,
                          float* __restrict__ asrc, float* __restrict__ adst,
                          int n, int C, int rowStride) {
    int idx = blockIdx.x * blockDim.x + threadIdx.x;
    if (idx >= n * HEADS) return;
    int node = idx >> 2, h = idx & 3;
    const unsigned short* row = Hm + (size_t)node * rowStride + h * C;
    const float* as = a_s + h * C;
    const float* ad = a_d + h * C;
    float s = 0.f, d = 0.f;
    for (int c = 0; c < C; ++c) {
        float v = bf2f(row[c]);
        s = fmaf(v, as[c], s);
        d = fmaf(v, ad[c], d);
    }
    asrc[idx] = s;
    adst[idx] = d;
}

// ---------------- CSR build ----------------
__global__ void deg_hist(const int* __restrict__ ei, int E, int ET, int N,
                         int* __restrict__ deg) {
    int e = blockIdx.x * blockDim.x + threadIdx.x;
    if (e >= ET) return;
    int d = (e < E) ? ei[E + e] : e - E;
    atomicAdd(&deg[d], 1);
}

__global__ void scan_block(const int* __restrict__ in, int* __restrict__ out,
                           int* __restrict__ bsum, int n) {
    __shared__ int tmp[256];
    int i = blockIdx.x * 256 + threadIdx.x;
    int v = (i < n) ? in[i] : 0;
    tmp[threadIdx.x] = v;
    __syncthreads();
    for (int d = 1; d < 256; d <<= 1) {
        int t = (threadIdx.x >= d) ? tmp[threadIdx.x - d] : 0;
        __syncthreads();
        tmp[threadIdx.x] += t;
        __syncthreads();
    }
    if (i < n) out[i] = tmp[threadIdx.x] - v;
    if (threadIdx.x == 255) bsum[blockIdx.x] = tmp[255];
}

__global__ void scan_bsum(int* bsum, int nb) {
    __shared__ int tmp[256];
    int v = (threadIdx.x < nb) ? bsum[threadIdx.x] : 0;
    tmp[threadIdx.x] = v;
    __syncthreads();
    for (int d = 1; d < 256; d <<= 1) {
        int t = (threadIdx.x >= d) ? tmp[threadIdx.x - d] : 0;
        __syncthreads();
        tmp[threadIdx.x] += t;
        __syncthreads();
    }
    if (threadIdx.x < nb) bsum[threadIdx.x] = tmp[threadIdx.x] - v;
}

__global__ void scan_add(int* out, const int* __restrict__ bsum, int n) {
    int i = blockIdx.x * 256 + threadIdx.x;
    if (i < n) out[i] += bsum[blockIdx.x];
}

__global__ void csr_fill(const int* __restrict__ ei, int E, int ET,
                         const int* __restrict__ rowptr, int* __restrict__ cur,
                         int* __restrict__ adj, int* __restrict__ dstOf) {
    int e = blockIdx.x * blockDim.x + threadIdx.x;
    if (e >= ET) return;
    int s, d;
    if (e < E) { s = ei[e]; d = ei[E + e]; } else { s = d = e - E; }
    int pos = rowptr[d] + atomicAdd(&cur[d], 1);
    adj[pos] = s;
    dstOf[pos] = d;
}

// ---------------- per-edge softmax numerators (CSR position order) ----------------
// P[j][h] = exp(lrelu(asrc[adj[j]][h] + adst[dstOf[j]][h])), no max shift.
__global__ void edge_w(const int* __restrict__ adj, const int* __restrict__ dstOf,
                       int ET, const float* __restrict__ asrc,
                       const float* __restrict__ adst, float* __restrict__ P) {
    int j = blockIdx.x * blockDim.x + threadIdx.x;
    if (j >= ET) return;
    int s = adj[j], d = dstOf[j];
    float4 av = *(const float4*)&asrc[(size_t)s * 4];
    float4 dv = *(const float4*)&adst[(size_t)d * 4];
    float4 p;
    p.x = __expf(lrelu(av.x + dv.x));
    p.y = __expf(lrelu(av.y + dv.y));
    p.z = __expf(lrelu(av.z + dv.z));
    p.w = __expf(lrelu(av.w + dv.w));
    *(float4*)&P[(size_t)j * 4] = p;
}

// ---------------- fused gather (HC=128): one wave per dst node, single pass ----------------
// 4 edges x 16 lanes x 8 channels. Hb row stride 256: [0,128)=h, [128,256)=lin.
__global__ __launch_bounds__(256) void gat_gather128(
    const int* __restrict__ rowptr, const int* __restrict__ adj, int ET,
    const float* __restrict__ P, const unsigned short* __restrict__ Hb,
    const float* __restrict__ bias, const float* __restrict__ lbias,
    unsigned short* __restrict__ xout, int n)
{
    int node = (blockIdx.x * 256 + threadIdx.x) >> 6;
    int lane = threadIdx.x & 63;
    if (node >= n) return;
    int beg = rowptr[node];
    int end = (node + 1 < n) ? rowptr[node + 1] : ET;

    int ep = lane >> 4;          // 0..3 edge slot
    int q  = lane & 15;          // channel block
    int c0 = q * 8;              // 8 channels per lane
    int h  = q >> 2;             // head

    float accp = 0.f;
    float a[8];
#pragma unroll
    for (int k = 0; k < 8; ++k) a[k] = 0.f;

    for (int j = beg + ep; j < end; j += 4) {
        int s = adj[j];
        float p = P[(size_t)j * 4 + h];
        accp += p;
        short8v hv = *(const short8v*)&Hb[(size_t)s * 256 + c0];
#pragma unroll
        for (int k = 0; k < 8; ++k)
            a[k] = fmaf(p, bf2f((unsigned short)hv[k]), a[k]);
    }
    // combine the 4 edge slots
#pragma unroll
    for (int off = 16; off <= 32; off <<= 1) {
        accp += __shfl_xor(accp, off);
#pragma unroll
        for (int k = 0; k < 8; ++k) a[k] += __shfl_xor(a[k], off);
    }

    if (ep == 0) {
        float inv = 1.f / (accp + 1e-16f);
        short8v lv = *(const short8v*)&Hb[(size_t)node * 256 + 128 + c0];
        unsigned short w[8];
#pragma unroll
        for (int k = 0; k < 8; ++k) {
            float v = a[k] * inv + bias[c0 + k] + bf2f((unsigned short)lv[k]) + lbias[c0 + k];
            v = v > 0.f ? v : __expf(v) - 1.f;
            w[k] = f2bf(v);
        }
        *(short8v*)&xout[(size_t)node * 128 + c0] = *(short8v*)w;
    }
}

// ---------------- fused gather layer 3 (C=10, mean over heads) ----------------
// 2 edges x 20 lane-pairs x 2 channels. Hb3 stride 64: [0,40)=h, [40,50)=lin, pad 0.
__global__ __launch_bounds__(256) void gat_gather40(
    const int* __restrict__ rowptr, const int* __restrict__ adj, int ET,
    const float* __restrict__ P, const unsigned short* __restrict__ Hb3,
    const float* __restrict__ bias, const float* __restrict__ lbias,
    float* __restrict__ out, int n)
{
    int node = (blockIdx.x * 256 + threadIdx.x) >> 6;
    int lane = threadIdx.x & 63;
    if (node >= n) return;
    int beg = rowptr[node];
    int end = (node + 1 < n) ? rowptr[node + 1] : ET;

    int ep  = lane >> 5;                 // 0..1 edge slot
    int sub = lane & 31;                 // 0..31; active sub<20
    int act = sub < 20;
    int c0  = act ? sub * 2 : 0;         // channels c0, c0+1 (never straddle a head)
    int h   = act ? (sub / 5) : 0;

    float accp = 0.f, a0 = 0.f, a1 = 0.f;
    for (int j = beg + ep; j < end; j += 2) {
        int s = adj[j];
        float p = P[(size_t)j * 4 + h];
        accp += p;
        ushort2 hv = *(const ushort2*)&Hb3[(size_t)s * 64 + c0];
        a0 = fmaf(p, bf2f(hv.x), a0);
        a1 = fmaf(p, bf2f(hv.y), a1);
    }
    accp += __shfl_xor(accp, 32);
    a0   += __shfl_xor(a0, 32);
    a1   += __shfl_xor(a1, 32);

    float inv = 0.25f / (accp + 1e-16f);
    a0 *= inv;
    a1 *= inv;

    // output channel c = lane (<10) collects Hb3-channels 10h+c from owning lanes
    float r = 0.f;
#pragma unroll
    for (int hh = 0; hh < 4; ++hh) {
        int ch = hh * 10 + lane;         // well-defined for lane<10; others unused
        float lo = __shfl(a0, ch >> 1);
        float hi = __shfl(a1, ch >> 1);
        r += (ch & 1) ? hi : lo;
    }
    if (lane < 10) {
        size_t o = (size_t)node * 10 + lane;
        float lin = bf2f(Hb3[(size_t)node * 64 + 40 + lane]);
        out[o] = r + bias[lane] + lin + lbias[lane];
    }
}

extern "C" void kernel_launch(void* const* d_in, const int* in_sizes, int n_in,
                              void* d_out, int out_size, void* d_ws, size_t ws_size,
                              hipStream_t stream) {
    const float* x   = (const float*)d_in[0];
    const int*   ei  = (const int*)d_in[1];
    const float* W1  = (const float*)d_in[2];
    const float* a1s = (const float*)d_in[3];
    const float* a1d = (const float*)d_in[4];
    const float* b1  = (const float*)d_in[5];
    const float* l1W = (const float*)d_in[6];
    const float* l1b = (const float*)d_in[7];
    const float* W2  = (const float*)d_in[8];
    const float* a2s = (const float*)d_in[9];
    const float* a2d = (const float*)d_in[10];
    const float* b2  = (const float*)d_in[11];
    const float* l2W = (const float*)d_in[12];
    const float* l2b = (const float*)d_in[13];
    const float* W3  = (const float*)d_in[14];
    const float* a3s = (const float*)d_in[15];
    const float* a3d = (const float*)d_in[16];
    const float* b3  = (const float*)d_in[17];
    const float* l3W = (const float*)d_in[18];
    const float* l3b = (const float*)d_in[19];

    const int N  = in_sizes[0] / 128;
    const int E  = in_sizes[1] / 2;
    const int ET = E + N;

    unsigned short* Xb = (unsigned short*)d_ws;           // N*128 bf16
    unsigned short* Hb = Xb + (size_t)N * 128;            // N*256 bf16
    unsigned short* BT = Hb + (size_t)N * 256;            // 256*128 bf16
    float* asrc = (float*)(BT + 256 * 128);               // N*4
    float* adst = asrc + (size_t)N * 4;                   // N*4
    float* P    = adst + (size_t)N * 4;                   // ET*4
    int* deg    = (int*)(P + (size_t)ET * 4);
    int* rowptr = deg + N;
    int* cur    = rowptr + N;
    int* bsum   = cur + N;
    int* adj    = bsum + 256;                             // ET
    int* dstOf  = adj + ET;                               // ET

    const int nScanBlocks = (N + 255) / 256;
    int alphaBlocks = (N * HEADS + 255) / 256;
    int edgeBlocks  = (ET + 255) / 256;
    int waveBlocks  = (N * 64 + 255) / 256;
    int rowBlocks   = (N + 63) / 64;

    // ---------- CSR build (shared by all 3 layers) ----------
    hipMemsetAsync(deg, 0, (size_t)N * 4, stream);
    hipMemsetAsync(cur, 0, (size_t)N * 4, stream);
    deg_hist<<<edgeBlocks, 256, 0, stream>>>(ei, E, ET, N, deg);
    scan_block<<<nScanBlocks, 256, 0, stream>>>(deg, rowptr, bsum, N);
    scan_bsum<<<1, 256, 0, stream>>>(bsum, nScanBlocks);
    scan_add<<<nScanBlocks, 256, 0, stream>>>(rowptr, bsum, N);
    csr_fill<<<edgeBlocks, 256, 0, stream>>>(ei, E, ET, rowptr, cur, adj, dstOf);

    castX<<<(N * 32 + 255) / 256, 256, 0, stream>>>(x, Xb, N * 32);

    // ---------- layer 1 ----------
    packB12<<<(256 * 128 + 255) / 256, 256, 0, stream>>>(W1, l1W, BT);
    mfma_gemm<<<dim3(4, rowBlocks), 256, 0, stream>>>(Xb, BT, Hb, N, 256);
    alpha32<<<alphaBlocks, 256, 0, stream>>>(Hb, a1s, a1d, asrc, adst, N);
    edge_w<<<edgeBlocks, 256, 0, stream>>>(adj, dstOf, ET, asrc, adst, P);
    gat_gather128<<<waveBlocks, 256, 0, stream>>>(rowptr, adj, ET, P, Hb, b1, l1b, Xb, N);

    // ---------- layer 2 ----------
    packB12<<<(256 * 128 + 255) / 256, 256, 0, stream>>>(W2, l2W, BT);
    mfma_gemm<<<dim3(4, rowBlocks), 256, 0, stream>>>(Xb, BT, Hb, N, 256);
    alpha32<<<alphaBlocks, 256, 0, stream>>>(Hb, a2s, a2d, asrc, adst, N);
    edge_w<<<edgeBlocks, 256, 0, stream>>>(adj, dstOf, ET, asrc, adst, P);
    gat_gather128<<<waveBlocks, 256, 0, stream>>>(rowptr, adj, ET, P, Hb, b2, l2b, Xb, N);

    // ---------- layer 3 ----------
    packB3<<<(64 * 128 + 255) / 256, 256, 0, stream>>>(W3, l3W, BT);
    mfma_gemm<<<dim3(1, rowBlocks), 256, 0, stream>>>(Xb, BT, Hb, N, 64);
    alpha_gen<<<alphaBlocks, 256, 0, stream>>>(Hb, a3s, a3d, asrc, adst, N, 10, 64);
    edge_w<<<edgeBlocks, 256, 0, stream>>>(adj, dstOf, ET, asrc, adst, P);
    gat_gather40<<<waveBlocks, 256, 0, stream>>>(rowptr, adj, ET, P, Hb, b3, l3b, (float*)d_out, N);
}

// Round 5
// 353.206 us; speedup vs baseline: 12.0105x; 1.0868x over previous
//
#include <hip/hip_runtime.h>
#include <math.h>

// 3-layer GAT. Round 5: int2 CSR (single 8B scattered store, self-loops placed
// without atomics), alpha coefficients fused into the MFMA GEMM as extra
// columns (Wa = W @ a), software-pipelined gathers. bf16 feature path.

#define HEADS 4

typedef __attribute__((ext_vector_type(8))) short short8v;   // 8 bf16
typedef __attribute__((ext_vector_type(4))) float float4v;   // 4 fp32 acc

__device__ __forceinline__ float lrelu(float v) { return v > 0.f ? v : 0.2f * v; }

__device__ __forceinline__ unsigned short f2bf(float f) {
    unsigned u = __float_as_uint(f);
    unsigned r = u + 0x7FFFu + ((u >> 16) & 1u);   // RNE
    return (unsigned short)(r >> 16);
}
__device__ __forceinline__ float bf2f(unsigned short u) {
    return __uint_as_float(((unsigned)u) << 16);
}

// ---------------- pack / cast kernels ----------------
__global__ void castX(const float* __restrict__ x, unsigned short* __restrict__ xb, int n4) {
    int i = blockIdx.x * blockDim.x + threadIdx.x;
    if (i >= n4) return;
    float4 v = *(const float4*)&x[(size_t)i * 4];
    ushort4 o;
    o.x = f2bf(v.x); o.y = f2bf(v.y); o.z = f2bf(v.z); o.w = f2bf(v.w);
    *(ushort4*)&xb[(size_t)i * 4] = o;
}

// BT has (256+64) rows x 128 k. rows 0..127 = W cols, 128..255 = LW cols,
// 256..259 = W@a_s per head, 260..263 = W@a_d per head, rest 0.
__global__ void packB12(const float* __restrict__ W, const float* __restrict__ LW,
                        const float* __restrict__ a_s, const float* __restrict__ a_d,
                        unsigned short* __restrict__ BT) {
    int i = blockIdx.x * blockDim.x + threadIdx.x;
    if (i >= 320 * 128) return;
    int m = i >> 7, k = i & 127;
    float v = 0.f;
    if (m < 128) {
        v = W[(size_t)k * 128 + m];
    } else if (m < 256) {
        v = LW[(size_t)k * 128 + (m - 128)];
    } else if (m < 260) {
        int h = m - 256;
        for (int c = 0; c < 32; ++c)
            v = fmaf(W[(size_t)k * 128 + h * 32 + c], a_s[h * 32 + c], v);
    } else if (m < 264) {
        int h = m - 260;
        for (int c = 0; c < 32; ++c)
            v = fmaf(W[(size_t)k * 128 + h * 32 + c], a_d[h * 32 + c], v);
    }
    BT[i] = f2bf(v);
}

// BT3 has (64+64) rows x 128 k. rows 0..39 = W3 cols, 40..49 = LW3 cols,
// 64..67 = W3@a_s per head, 68..71 = W3@a_d, rest 0.
__global__ void packB3(const float* __restrict__ W3, const float* __restrict__ LW3,
                       const float* __restrict__ a_s, const float* __restrict__ a_d,
                       unsigned short* __restrict__ BT) {
    int i = blockIdx.x * blockDim.x + threadIdx.x;
    if (i >= 128 * 128) return;
    int m = i >> 7, k = i & 127;
    float v = 0.f;
    if (m < 40) {
        v = W3[(size_t)k * 40 + m];
    } else if (m < 50) {
        v = LW3[(size_t)k * 10 + (m - 40)];
    } else if (m >= 64 && m < 68) {
        int h = m - 64;
        for (int c = 0; c < 10; ++c)
            v = fmaf(W3[(size_t)k * 40 + h * 10 + c], a_s[h * 10 + c], v);
    } else if (m >= 68 && m < 72) {
        int h = m - 68;
        for (int c = 0; c < 10; ++c)
            v = fmaf(W3[(size_t)k * 40 + h * 10 + c], a_d[h * 10 + c], v);
    }
    BT[i] = f2bf(v);
}

// ---------------- MFMA GEMM with fused alpha columns ----------------
// C[n][Mc] = A[n][128] @ BT[0..Mc)[128]^T ; col-block at col0==Mc computes
// asrc/adst (BT rows Mc..Mc+8). grid.x = Mc/64 + 1.
__global__ __launch_bounds__(256) void mfma_gemm(const unsigned short* __restrict__ A,
                                                 const unsigned short* __restrict__ BT,
                                                 unsigned short* __restrict__ C,
                                                 float* __restrict__ asrc,
                                                 float* __restrict__ adst,
                                                 int nrows, int Mc) {
    const int wave = threadIdx.x >> 6;
    const int lane = threadIdx.x & 63;
    const int row0 = blockIdx.y * 64 + wave * 16;
    const int col0 = blockIdx.x * 64;
    const int lrow = lane & 15;
    const int kgrp = lane >> 4;
    const bool alphaBlk = (col0 >= Mc);

    float4v acc0 = {0.f, 0.f, 0.f, 0.f};
    float4v acc1 = {0.f, 0.f, 0.f, 0.f};
    float4v acc2 = {0.f, 0.f, 0.f, 0.f};
    float4v acc3 = {0.f, 0.f, 0.f, 0.f};

    int arow = row0 + lrow;
    if (arow >= nrows) arow = nrows - 1;
    const unsigned short* Ap = A + (size_t)arow * 128 + kgrp * 8;
    const unsigned short* Bp = BT + (size_t)(col0 + lrow) * 128 + kgrp * 8;

    if (alphaBlk) {
#pragma unroll
        for (int t = 0; t < 4; ++t) {
            short8v a  = *(const short8v*)(Ap + t * 32);
            short8v b0 = *(const short8v*)(Bp + t * 32);
            acc0 = __builtin_amdgcn_mfma_f32_16x16x32_bf16(a, b0, acc0, 0, 0, 0);
        }
        if (lrow < 8) {
            float* dst = (lrow < 4) ? asrc : adst;
            int hh = lrow & 3;
#pragma unroll
            for (int r = 0; r < 4; ++r) {
                int row = row0 + kgrp * 4 + r;
                if (row < nrows) dst[(size_t)row * 4 + hh] = acc0[r];
            }
        }
        return;
    }

#pragma unroll
    for (int t = 0; t < 4; ++t) {
        short8v a  = *(const short8v*)(Ap + t * 32);
        short8v b0 = *(const short8v*)(Bp + t * 32);
        short8v b1 = *(const short8v*)(Bp + 16 * 128 + t * 32);
        short8v b2 = *(const short8v*)(Bp + 32 * 128 + t * 32);
        short8v b3 = *(const short8v*)(Bp + 48 * 128 + t * 32);
        acc0 = __builtin_amdgcn_mfma_f32_16x16x32_bf16(a, b0, acc0, 0, 0, 0);
        acc1 = __builtin_amdgcn_mfma_f32_16x16x32_bf16(a, b1, acc1, 0, 0, 0);
        acc2 = __builtin_amdgcn_mfma_f32_16x16x32_bf16(a, b2, acc2, 0, 0, 0);
        acc3 = __builtin_amdgcn_mfma_f32_16x16x32_bf16(a, b3, acc3, 0, 0, 0);
    }

#pragma unroll
    for (int r = 0; r < 4; ++r) {
        int row = row0 + kgrp * 4 + r;
        if (row >= nrows) continue;
        size_t base = (size_t)row * Mc + col0 + lrow;
        C[base]      = f2bf(acc0[r]);
        C[base + 16] = f2bf(acc1[r]);
        C[base + 32] = f2bf(acc2[r]);
        C[base + 48] = f2bf(acc3[r]);
    }
}

// ---------------- CSR build ----------------
__global__ void deg_hist(const int* __restrict__ ei, int E, int* __restrict__ deg) {
    int e = blockIdx.x * blockDim.x + threadIdx.x;
    if (e >= E) return;
    atomicAdd(&deg[ei[E + e]], 1);
}

// exclusive scan of (deg[i]+1): each node's segment = deg edges + 1 self-loop
__global__ void scan_block(const int* __restrict__ in, int* __restrict__ out,
                           int* __restrict__ bsum, int n) {
    __shared__ int tmp[256];
    int i = blockIdx.x * 256 + threadIdx.x;
    int v = (i < n) ? in[i] + 1 : 0;
    tmp[threadIdx.x] = v;
    __syncthreads();
    for (int d = 1; d < 256; d <<= 1) {
        int t = (threadIdx.x >= d) ? tmp[threadIdx.x - d] : 0;
        __syncthreads();
        tmp[threadIdx.x] += t;
        __syncthreads();
    }
    if (i < n) out[i] = tmp[threadIdx.x] - v;
    if (threadIdx.x == 255) bsum[blockIdx.x] = tmp[255];
}

__global__ void scan_bsum(int* bsum, int nb) {
    __shared__ int tmp[256];
    int v = (threadIdx.x < nb) ? bsum[threadIdx.x] : 0;
    tmp[threadIdx.x] = v;
    __syncthreads();
    for (int d = 1; d < 256; d <<= 1) {
        int t = (threadIdx.x >= d) ? tmp[threadIdx.x - d] : 0;
        __syncthreads();
        tmp[threadIdx.x] += t;
        __syncthreads();
    }
    if (threadIdx.x < nb) bsum[threadIdx.x] = tmp[threadIdx.x] - v;
}

__global__ void scan_add(int* out, const int* __restrict__ bsum, int n) {
    int i = blockIdx.x * 256 + threadIdx.x;
    if (i < n) out[i] += bsum[blockIdx.x];
}

// self-loop occupies the first slot of each node's segment (no atomics)
__global__ void selfloop_fill(const int* __restrict__ rowptr, int2* __restrict__ adjdst, int n) {
    int i = blockIdx.x * blockDim.x + threadIdx.x;
    if (i >= n) return;
    adjdst[rowptr[i]] = make_int2(i, i);
}

__global__ void csr_fill_e(const int* __restrict__ ei, int E,
                           const int* __restrict__ rowptr, int* __restrict__ cur,
                           int2* __restrict__ adjdst) {
    int e = blockIdx.x * blockDim.x + threadIdx.x;
    if (e >= E) return;
    int s = ei[e], d = ei[E + e];
    int pos = rowptr[d] + 1 + atomicAdd(&cur[d], 1);
    adjdst[pos] = make_int2(s, d);
}

// ---------------- per-edge softmax numerators (CSR position order) ----------------
__global__ void edge_w(const int2* __restrict__ adjdst, int ET,
                       const float* __restrict__ asrc,
                       const float* __restrict__ adst, float* __restrict__ P) {
    int j = blockIdx.x * blockDim.x + threadIdx.x;
    if (j >= ET) return;
    int2 sd = adjdst[j];
    float4 av = *(const float4*)&asrc[(size_t)sd.x * 4];
    float4 dv = *(const float4*)&adst[(size_t)sd.y * 4];
    float4 p;
    p.x = __expf(lrelu(av.x + dv.x));
    p.y = __expf(lrelu(av.y + dv.y));
    p.z = __expf(lrelu(av.z + dv.z));
    p.w = __expf(lrelu(av.w + dv.w));
    *(float4*)&P[(size_t)j * 4] = p;
}

// ---------------- fused gather (HC=128): one wave per dst node ----------------
// 4 edge slots x 16 lanes x 8 channels; software-pipelined.
__global__ __launch_bounds__(256) void gat_gather128(
    const int* __restrict__ rowptr, const int2* __restrict__ adjdst, int ET,
    const float* __restrict__ P, const unsigned short* __restrict__ Hb,
    const float* __restrict__ bias, const float* __restrict__ lbias,
    unsigned short* __restrict__ xout, int n)
{
    int node = (blockIdx.x * 256 + threadIdx.x) >> 6;
    int lane = threadIdx.x & 63;
    if (node >= n) return;
    int beg = rowptr[node];
    int end = (node + 1 < n) ? rowptr[node + 1] : ET;

    int ep = lane >> 4;          // edge slot 0..3
    int q  = lane & 15;          // channel block
    int c0 = q * 8;
    int h  = q >> 2;

    float accp = 0.f;
    float a[8];
#pragma unroll
    for (int k = 0; k < 8; ++k) a[k] = 0.f;

    int j = beg + ep;
    int sN = 0; float pN = 0.f;
    bool valid = j < end;
    if (valid) { sN = adjdst[j].x; pN = P[(size_t)j * 4 + h]; }
    while (valid) {
        int s = sN; float p = pN;
        int j2 = j + 4;
        bool v2 = j2 < end;
        if (v2) { sN = adjdst[j2].x; pN = P[(size_t)j2 * 4 + h]; }
        short8v hv = *(const short8v*)&Hb[(size_t)s * 256 + c0];
        accp += p;
#pragma unroll
        for (int k = 0; k < 8; ++k)
            a[k] = fmaf(p, bf2f((unsigned short)hv[k]), a[k]);
        j = j2; valid = v2;
    }
#pragma unroll
    for (int off = 16; off <= 32; off <<= 1) {
        accp += __shfl_xor(accp, off);
#pragma unroll
        for (int k = 0; k < 8; ++k) a[k] += __shfl_xor(a[k], off);
    }

    if (ep == 0) {
        float inv = 1.f / (accp + 1e-16f);
        short8v lv = *(const short8v*)&Hb[(size_t)node * 256 + 128 + c0];
        unsigned short w[8];
#pragma unroll
        for (int k = 0; k < 8; ++k) {
            float v = a[k] * inv + bias[c0 + k] + bf2f((unsigned short)lv[k]) + lbias[c0 + k];
            v = v > 0.f ? v : __expf(v) - 1.f;
            w[k] = f2bf(v);
        }
        *(short8v*)&xout[(size_t)node * 128 + c0] = *(short8v*)w;
    }
}

// ---------------- fused gather layer 3 (C=10, mean over heads) ----------------
// 2 edge slots x 20 lane-pairs x 2 channels. Hb3 stride 64: [0,40)=h, [40,50)=lin.
__global__ __launch_bounds__(256) void gat_gather40(
    const int* __restrict__ rowptr, const int2* __restrict__ adjdst, int ET,
    const float* __restrict__ P, const unsigned short* __restrict__ Hb3,
    const float* __restrict__ bias, const float* __restrict__ lbias,
    float* __restrict__ out, int n)
{
    int node = (blockIdx.x * 256 + threadIdx.x) >> 6;
    int lane = threadIdx.x & 63;
    if (node >= n) return;
    int beg = rowptr[node];
    int end = (node + 1 < n) ? rowptr[node + 1] : ET;

    int ep  = lane >> 5;
    int sub = lane & 31;
    int act = sub < 20;
    int c0  = act ? sub * 2 : 0;
    int h   = act ? (sub / 5) : 0;

    float accp = 0.f, a0 = 0.f, a1 = 0.f;
    int j = beg + ep;
    int sN = 0; float pN = 0.f;
    bool valid = j < end;
    if (valid) { sN = adjdst[j].x; pN = P[(size_t)j * 4 + h]; }
    while (valid) {
        int s = sN; float p = pN;
        int j2 = j + 2;
        bool v2 = j2 < end;
        if (v2) { sN = adjdst[j2].x; pN = P[(size_t)j2 * 4 + h]; }
        ushort2 hv = *(const ushort2*)&Hb3[(size_t)s * 64 + c0];
        accp += p;
        a0 = fmaf(p, bf2f(hv.x), a0);
        a1 = fmaf(p, bf2f(hv.y), a1);
        j = j2; valid = v2;
    }
    accp += __shfl_xor(accp, 32);
    a0   += __shfl_xor(a0, 32);
    a1   += __shfl_xor(a1, 32);

    float inv = 0.25f / (accp + 1e-16f);
    a0 *= inv;
    a1 *= inv;

    float r = 0.f;
#pragma unroll
    for (int hh = 0; hh < 4; ++hh) {
        int ch = hh * 10 + lane;
        float lo = __shfl(a0, ch >> 1);
        float hi = __shfl(a1, ch >> 1);
        r += (ch & 1) ? hi : lo;
    }
    if (lane < 10) {
        size_t o = (size_t)node * 10 + lane;
        float lin = bf2f(Hb3[(size_t)node * 64 + 40 + lane]);
        out[o] = r + bias[lane] + lin + lbias[lane];
    }
}

extern "C" void kernel_launch(void* const* d_in, const int* in_sizes, int n_in,
                              void* d_out, int out_size, void* d_ws, size_t ws_size,
                              hipStream_t stream) {
    const float* x   = (const float*)d_in[0];
    const int*   ei  = (const int*)d_in[1];
    const float* W1  = (const float*)d_in[2];
    const float* a1s = (const float*)d_in[3];
    const float* a1d = (const float*)d_in[4];
    const float* b1  = (const float*)d_in[5];
    const float* l1W = (const float*)d_in[6];
    const float* l1b = (const float*)d_in[7];
    const float* W2  = (const float*)d_in[8];
    const float* a2s = (const float*)d_in[9];
    const float* a2d = (const float*)d_in[10];
    const float* b2  = (const float*)d_in[11];
    const float* l2W = (const float*)d_in[12];
    const float* l2b = (const float*)d_in[13];
    const float* W3  = (const float*)d_in[14];
    const float* a3s = (const float*)d_in[15];
    const float* a3d = (const float*)d_in[16];
    const float* b3  = (const float*)d_in[17];
    const float* l3W = (const float*)d_in[18];
    const float* l3b = (const float*)d_in[19];

    const int N  = in_sizes[0] / 128;
    const int E  = in_sizes[1] / 2;
    const int ET = E + N;

    unsigned short* Xb = (unsigned short*)d_ws;           // N*128 bf16
    unsigned short* Hb = Xb + (size_t)N * 128;            // N*256 bf16
    unsigned short* BT = Hb + (size_t)N * 256;            // 320*128 bf16
    float* asrc = (float*)(BT + 320 * 128);               // N*4
    float* adst = asrc + (size_t)N * 4;                   // N*4
    float* P    = adst + (size_t)N * 4;                   // ET*4
    int* deg    = (int*)(P + (size_t)ET * 4);             // N
    int* cur    = deg + N;                                // N (adjacent for one memset)
    int* rowptr = cur + N;                                // N
    int* bsum   = rowptr + N;                             // 256
    int2* adjdst = (int2*)(bsum + 256);                   // ET int2

    const int nScanBlocks = (N + 255) / 256;
    int eBlocks   = (E + 255) / 256;
    int etBlocks  = (ET + 255) / 256;
    int nBlocks   = (N + 255) / 256;
    int waveBlocks = (N * 64 + 255) / 256;
    int rowBlocks  = (N + 63) / 64;

    // ---------- CSR build (shared by all 3 layers) ----------
    hipMemsetAsync(deg, 0, (size_t)N * 2 * 4, stream);    // deg + cur
    deg_hist<<<eBlocks, 256, 0, stream>>>(ei, E, deg);
    scan_block<<<nScanBlocks, 256, 0, stream>>>(deg, rowptr, bsum, N);
    scan_bsum<<<1, 256, 0, stream>>>(bsum, nScanBlocks);
    scan_add<<<nScanBlocks, 256, 0, stream>>>(rowptr, bsum, N);
    selfloop_fill<<<nBlocks, 256, 0, stream>>>(rowptr, adjdst, N);
    csr_fill_e<<<eBlocks, 256, 0, stream>>>(ei, E, rowptr, cur, adjdst);

    castX<<<(N * 32 + 255) / 256, 256, 0, stream>>>(x, Xb, N * 32);

    // ---------- layer 1 ----------
    packB12<<<(320 * 128 + 255) / 256, 256, 0, stream>>>(W1, l1W, a1s, a1d, BT);
    mfma_gemm<<<dim3(5, rowBlocks), 256, 0, stream>>>(Xb, BT, Hb, asrc, adst, N, 256);
    edge_w<<<etBlocks, 256, 0, stream>>>(adjdst, ET, asrc, adst, P);
    gat_gather128<<<waveBlocks, 256, 0, stream>>>(rowptr, adjdst, ET, P, Hb, b1, l1b, Xb, N);

    // ---------- layer 2 ----------
    packB12<<<(320 * 128 + 255) / 256, 256, 0, stream>>>(W2, l2W, a2s, a2d, BT);
    mfma_gemm<<<dim3(5, rowBlocks), 256, 0, stream>>>(Xb, BT, Hb, asrc, adst, N, 256);
    edge_w<<<etBlocks, 256, 0, stream>>>(adjdst, ET, asrc, adst, P);
    gat_gather128<<<waveBlocks, 256, 0, stream>>>(rowptr, adjdst, ET, P, Hb, b2, l2b, Xb, N);

    // ---------- layer 3 ----------
    packB3<<<(128 * 128 + 255) / 256, 256, 0, stream>>>(W3, l3W, a3s, a3d, BT);
    mfma_gemm<<<dim3(2, rowBlocks), 256, 0, stream>>>(Xb, BT, Hb, asrc, adst, N, 64);
    edge_w<<<etBlocks, 256, 0, stream>>>(adjdst, ET, asrc, adst, P);
    gat_gather40<<<waveBlocks, 256, 0, stream>>>(rowptr, adjdst, ET, P, Hb, b3, l3b, (float*)d_out, N);
}

// Round 6
// 341.483 us; speedup vs baseline: 12.4228x; 1.0343x over previous
//
#include <hip/hip_runtime.h>
#include <math.h>

// 3-layer GAT. Round 6: XCD-bucketed CSR fill (blockIdx&7 buckets over dst
// ranges -> each adjdst line dirtied in one XCD's L2 only, killing the 8x
// writeback duplication). Self-loops folded into the same kernel. int4
// deg_hist. Alpha fused in MFMA GEMM; per-edge softmax numerators; fused
// gathers. bf16 feature path.

#define HEADS 4

typedef __attribute__((ext_vector_type(8))) short short8v;   // 8 bf16
typedef __attribute__((ext_vector_type(4))) float float4v;   // 4 fp32 acc

__device__ __forceinline__ float lrelu(float v) { return v > 0.f ? v : 0.2f * v; }

__device__ __forceinline__ unsigned short f2bf(float f) {
    unsigned u = __float_as_uint(f);
    unsigned r = u + 0x7FFFu + ((u >> 16) & 1u);   // RNE
    return (unsigned short)(r >> 16);
}
__device__ __forceinline__ float bf2f(unsigned short u) {
    return __uint_as_float(((unsigned)u) << 16);
}

// ---------------- pack / cast kernels ----------------
__global__ void castX(const float* __restrict__ x, unsigned short* __restrict__ xb, int n4) {
    int i = blockIdx.x * blockDim.x + threadIdx.x;
    if (i >= n4) return;
    float4 v = *(const float4*)&x[(size_t)i * 4];
    ushort4 o;
    o.x = f2bf(v.x); o.y = f2bf(v.y); o.z = f2bf(v.z); o.w = f2bf(v.w);
    *(ushort4*)&xb[(size_t)i * 4] = o;
}

// BT has (256+64) rows x 128 k. rows 0..127 = W cols, 128..255 = LW cols,
// 256..259 = W@a_s per head, 260..263 = W@a_d per head, rest 0.
__global__ void packB12(const float* __restrict__ W, const float* __restrict__ LW,
                        const float* __restrict__ a_s, const float* __restrict__ a_d,
                        unsigned short* __restrict__ BT) {
    int i = blockIdx.x * blockDim.x + threadIdx.x;
    if (i >= 320 * 128) return;
    int m = i >> 7, k = i & 127;
    float v = 0.f;
    if (m < 128) {
        v = W[(size_t)k * 128 + m];
    } else if (m < 256) {
        v = LW[(size_t)k * 128 + (m - 128)];
    } else if (m < 260) {
        int h = m - 256;
        for (int c = 0; c < 32; ++c)
            v = fmaf(W[(size_t)k * 128 + h * 32 + c], a_s[h * 32 + c], v);
    } else if (m < 264) {
        int h = m - 260;
        for (int c = 0; c < 32; ++c)
            v = fmaf(W[(size_t)k * 128 + h * 32 + c], a_d[h * 32 + c], v);
    }
    BT[i] = f2bf(v);
}

// BT3 has (64+64) rows x 128 k. rows 0..39 = W3 cols, 40..49 = LW3 cols,
// 64..67 = W3@a_s per head, 68..71 = W3@a_d, rest 0.
__global__ void packB3(const float* __restrict__ W3, const float* __restrict__ LW3,
                       const float* __restrict__ a_s, const float* __restrict__ a_d,
                       unsigned short* __restrict__ BT) {
    int i = blockIdx.x * blockDim.x + threadIdx.x;
    if (i >= 128 * 128) return;
    int m = i >> 7, k = i & 127;
    float v = 0.f;
    if (m < 40) {
        v = W3[(size_t)k * 40 + m];
    } else if (m < 50) {
        v = LW3[(size_t)k * 10 + (m - 40)];
    } else if (m >= 64 && m < 68) {
        int h = m - 64;
        for (int c = 0; c < 10; ++c)
            v = fmaf(W3[(size_t)k * 40 + h * 10 + c], a_s[h * 10 + c], v);
    } else if (m >= 68 && m < 72) {
        int h = m - 68;
        for (int c = 0; c < 10; ++c)
            v = fmaf(W3[(size_t)k * 40 + h * 10 + c], a_d[h * 10 + c], v);
    }
    BT[i] = f2bf(v);
}

// ---------------- MFMA GEMM with fused alpha columns ----------------
__global__ __launch_bounds__(256) void mfma_gemm(const unsigned short* __restrict__ A,
                                                 const unsigned short* __restrict__ BT,
                                                 unsigned short* __restrict__ C,
                                                 float* __restrict__ asrc,
                                                 float* __restrict__ adst,
                                                 int nrows, int Mc) {
    const int wave = threadIdx.x >> 6;
    const int lane = threadIdx.x & 63;
    const int row0 = blockIdx.y * 64 + wave * 16;
    const int col0 = blockIdx.x * 64;
    const int lrow = lane & 15;
    const int kgrp = lane >> 4;
    const bool alphaBlk = (col0 >= Mc);

    float4v acc0 = {0.f, 0.f, 0.f, 0.f};
    float4v acc1 = {0.f, 0.f, 0.f, 0.f};
    float4v acc2 = {0.f, 0.f, 0.f, 0.f};
    float4v acc3 = {0.f, 0.f, 0.f, 0.f};

    int arow = row0 + lrow;
    if (arow >= nrows) arow = nrows - 1;
    const unsigned short* Ap = A + (size_t)arow * 128 + kgrp * 8;
    const unsigned short* Bp = BT + (size_t)(col0 + lrow) * 128 + kgrp * 8;

    if (alphaBlk) {
#pragma unroll
        for (int t = 0; t < 4; ++t) {
            short8v a  = *(const short8v*)(Ap + t * 32);
            short8v b0 = *(const short8v*)(Bp + t * 32);
            acc0 = __builtin_amdgcn_mfma_f32_16x16x32_bf16(a, b0, acc0, 0, 0, 0);
        }
        if (lrow < 8) {
            float* dst = (lrow < 4) ? asrc : adst;
            int hh = lrow & 3;
#pragma unroll
            for (int r = 0; r < 4; ++r) {
                int row = row0 + kgrp * 4 + r;
                if (row < nrows) dst[(size_t)row * 4 + hh] = acc0[r];
            }
        }
        return;
    }

#pragma unroll
    for (int t = 0; t < 4; ++t) {
        short8v a  = *(const short8v*)(Ap + t * 32);
        short8v b0 = *(const short8v*)(Bp + t * 32);
        short8v b1 = *(const short8v*)(Bp + 16 * 128 + t * 32);
        short8v b2 = *(const short8v*)(Bp + 32 * 128 + t * 32);
        short8v b3 = *(const short8v*)(Bp + 48 * 128 + t * 32);
        acc0 = __builtin_amdgcn_mfma_f32_16x16x32_bf16(a, b0, acc0, 0, 0, 0);
        acc1 = __builtin_amdgcn_mfma_f32_16x16x32_bf16(a, b1, acc1, 0, 0, 0);
        acc2 = __builtin_amdgcn_mfma_f32_16x16x32_bf16(a, b2, acc2, 0, 0, 0);
        acc3 = __builtin_amdgcn_mfma_f32_16x16x32_bf16(a, b3, acc3, 0, 0, 0);
    }

#pragma unroll
    for (int r = 0; r < 4; ++r) {
        int row = row0 + kgrp * 4 + r;
        if (row >= nrows) continue;
        size_t base = (size_t)row * Mc + col0 + lrow;
        C[base]      = f2bf(acc0[r]);
        C[base + 16] = f2bf(acc1[r]);
        C[base + 32] = f2bf(acc2[r]);
        C[base + 48] = f2bf(acc3[r]);
    }
}

// ---------------- CSR build ----------------
__global__ void deg_hist4(const int* __restrict__ dst, int E, int* __restrict__ deg) {
    int e = (blockIdx.x * blockDim.x + threadIdx.x) * 4;
    if (e + 3 < E) {
        int4 d = *(const int4*)&dst[e];
        atomicAdd(&deg[d.x], 1);
        atomicAdd(&deg[d.y], 1);
        atomicAdd(&deg[d.z], 1);
        atomicAdd(&deg[d.w], 1);
    } else {
        for (; e < E; ++e) atomicAdd(&deg[dst[e]], 1);
    }
}

// exclusive scan of (deg[i]+1): each node's segment = 1 self-loop + deg edges
__global__ void scan_block(const int* __restrict__ in, int* __restrict__ out,
                           int* __restrict__ bsum, int n) {
    __shared__ int tmp[256];
    int i = blockIdx.x * 256 + threadIdx.x;
    int v = (i < n) ? in[i] + 1 : 0;
    tmp[threadIdx.x] = v;
    __syncthreads();
    for (int d = 1; d < 256; d <<= 1) {
        int t = (threadIdx.x >= d) ? tmp[threadIdx.x - d] : 0;
        __syncthreads();
        tmp[threadIdx.x] += t;
        __syncthreads();
    }
    if (i < n) out[i] = tmp[threadIdx.x] - v;
    if (threadIdx.x == 255) bsum[blockIdx.x] = tmp[255];
}

__global__ void scan_bsum(int* bsum, int nb) {
    __shared__ int tmp[256];
    int v = (threadIdx.x < nb) ? bsum[threadIdx.x] : 0;
    tmp[threadIdx.x] = v;
    __syncthreads();
    for (int d = 1; d < 256; d <<= 1) {
        int t = (threadIdx.x >= d) ? tmp[threadIdx.x - d] : 0;
        __syncthreads();
        tmp[threadIdx.x] += t;
        __syncthreads();
    }
    if (threadIdx.x < nb) bsum[threadIdx.x] = tmp[threadIdx.x] - v;
}

__global__ void scan_add(int* out, const int* __restrict__ bsum, int n) {
    int i = blockIdx.x * 256 + threadIdx.x;
    if (i < n) out[i] += bsum[blockIdx.x];
}

// XCD-bucketed CSR fill: bucket = blockIdx&7 over dst node ranges.
// Every (bucket, chunk) pair is statically covered -> correct for any
// blockIdx->XCD mapping; fast when %8 == XCD (round-robin dispatch).
#define FILL_U 8
__global__ __launch_bounds__(256) void csr_fill_bucket(
    const int* __restrict__ ei, int E, int N,
    const int* __restrict__ rowptr, int* __restrict__ cur,
    int2* __restrict__ adjdst)
{
    const int bucket = blockIdx.x & 7;
    const int grp    = blockIdx.x >> 3;
    const int ngrp   = gridDim.x >> 3;
    const int npb    = (N + 7) >> 3;
    const int lo = bucket * npb;
    const int hi = (lo + npb < N) ? lo + npb : N;

    // self-loops for this bucket's nodes (first slot of each segment)
    for (int i = lo + grp * 256 + (int)threadIdx.x; i < hi; i += ngrp * 256)
        adjdst[rowptr[i]] = make_int2(i, i);

    // edges: fixed-size chunks strided over this bucket's block group
    const int chunkSz = 256 * FILL_U;
    const int nchunks = (E + chunkSz - 1) / chunkSz;
    const int* dstRow = ei + E;
    for (int c = grp; c < nchunks; c += ngrp) {
        int base = c * chunkSz + (int)threadIdx.x;
#pragma unroll
        for (int k = 0; k < FILL_U; ++k) {
            int e = base + k * 256;
            if (e < E) {
                int d = dstRow[e];
                if (d >= lo && d < hi) {
                    int s = ei[e];
                    int pos = rowptr[d] + 1 + atomicAdd(&cur[d], 1);
                    adjdst[pos] = make_int2(s, d);
                }
            }
        }
    }
}

// ---------------- per-edge softmax numerators (CSR position order) ----------------
__global__ void edge_w(const int2* __restrict__ adjdst, int ET,
                       const float* __restrict__ asrc,
                       const float* __restrict__ adst, float* __restrict__ P) {
    int j = blockIdx.x * blockDim.x + threadIdx.x;
    if (j >= ET) return;
    int2 sd = adjdst[j];
    float4 av = *(const float4*)&asrc[(size_t)sd.x * 4];
    float4 dv = *(const float4*)&adst[(size_t)sd.y * 4];
    float4 p;
    p.x = __expf(lrelu(av.x + dv.x));
    p.y = __expf(lrelu(av.y + dv.y));
    p.z = __expf(lrelu(av.z + dv.z));
    p.w = __expf(lrelu(av.w + dv.w));
    *(float4*)&P[(size_t)j * 4] = p;
}

// ---------------- fused gather (HC=128): one wave per dst node ----------------
__global__ __launch_bounds__(256) void gat_gather128(
    const int* __restrict__ rowptr, const int2* __restrict__ adjdst, int ET,
    const float* __restrict__ P, const unsigned short* __restrict__ Hb,
    const float* __restrict__ bias, const float* __restrict__ lbias,
    unsigned short* __restrict__ xout, int n)
{
    int node = (blockIdx.x * 256 + threadIdx.x) >> 6;
    int lane = threadIdx.x & 63;
    if (node >= n) return;
    int beg = rowptr[node];
    int end = (node + 1 < n) ? rowptr[node + 1] : ET;

    int ep = lane >> 4;          // edge slot 0..3
    int q  = lane & 15;          // channel block
    int c0 = q * 8;
    int h  = q >> 2;

    float accp = 0.f;
    float a[8];
#pragma unroll
    for (int k = 0; k < 8; ++k) a[k] = 0.f;

    int j = beg + ep;
    int sN = 0; float pN = 0.f;
    bool valid = j < end;
    if (valid) { sN = adjdst[j].x; pN = P[(size_t)j * 4 + h]; }
    while (valid) {
        int s = sN; float p = pN;
        int j2 = j + 4;
        bool v2 = j2 < end;
        if (v2) { sN = adjdst[j2].x; pN = P[(size_t)j2 * 4 + h]; }
        short8v hv = *(const short8v*)&Hb[(size_t)s * 256 + c0];
        accp += p;
#pragma unroll
        for (int k = 0; k < 8; ++k)
            a[k] = fmaf(p, bf2f((unsigned short)hv[k]), a[k]);
        j = j2; valid = v2;
    }
#pragma unroll
    for (int off = 16; off <= 32; off <<= 1) {
        accp += __shfl_xor(accp, off);
#pragma unroll
        for (int k = 0; k < 8; ++k) a[k] += __shfl_xor(a[k], off);
    }

    if (ep == 0) {
        float inv = 1.f / (accp + 1e-16f);
        short8v lv = *(const short8v*)&Hb[(size_t)node * 256 + 128 + c0];
        unsigned short w[8];
#pragma unroll
        for (int k = 0; k < 8; ++k) {
            float v = a[k] * inv + bias[c0 + k] + bf2f((unsigned short)lv[k]) + lbias[c0 + k];
            v = v > 0.f ? v : __expf(v) - 1.f;
            w[k] = f2bf(v);
        }
        *(short8v*)&xout[(size_t)node * 128 + c0] = *(short8v*)w;
    }
}

// ---------------- fused gather layer 3 (C=10, mean over heads) ----------------
__global__ __launch_bounds__(256) void gat_gather40(
    const int* __restrict__ rowptr, const int2* __restrict__ adjdst, int ET,
    const float* __restrict__ P, const unsigned short* __restrict__ Hb3,
    const float* __restrict__ bias, const float* __restrict__ lbias,
    float* __restrict__ out, int n)
{
    int node = (blockIdx.x * 256 + threadIdx.x) >> 6;
    int lane = threadIdx.x & 63;
    if (node >= n) return;
    int beg = rowptr[node];
    int end = (node + 1 < n) ? rowptr[node + 1] : ET;

    int ep  = lane >> 5;
    int sub = lane & 31;
    int act = sub < 20;
    int c0  = act ? sub * 2 : 0;
    int h   = act ? (sub / 5) : 0;

    float accp = 0.f, a0 = 0.f, a1 = 0.f;
    int j = beg + ep;
    int sN = 0; float pN = 0.f;
    bool valid = j < end;
    if (valid) { sN = adjdst[j].x; pN = P[(size_t)j * 4 + h]; }
    while (valid) {
        int s = sN; float p = pN;
        int j2 = j + 2;
        bool v2 = j2 < end;
        if (v2) { sN = adjdst[j2].x; pN = P[(size_t)j2 * 4 + h]; }
        ushort2 hv = *(const ushort2*)&Hb3[(size_t)s * 64 + c0];
        accp += p;
        a0 = fmaf(p, bf2f(hv.x), a0);
        a1 = fmaf(p, bf2f(hv.y), a1);
        j = j2; valid = v2;
    }
    accp += __shfl_xor(accp, 32);
    a0   += __shfl_xor(a0, 32);
    a1   += __shfl_xor(a1, 32);

    float inv = 0.25f / (accp + 1e-16f);
    a0 *= inv;
    a1 *= inv;

    float r = 0.f;
#pragma unroll
    for (int hh = 0; hh < 4; ++hh) {
        int ch = hh * 10 + lane;
        float lo = __shfl(a0, ch >> 1);
        float hi = __shfl(a1, ch >> 1);
        r += (ch & 1) ? hi : lo;
    }
    if (lane < 10) {
        size_t o = (size_t)node * 10 + lane;
        float lin = bf2f(Hb3[(size_t)node * 64 + 40 + lane]);
        out[o] = r + bias[lane] + lin + lbias[lane];
    }
}

extern "C" void kernel_launch(void* const* d_in, const int* in_sizes, int n_in,
                              void* d_out, int out_size, void* d_ws, size_t ws_size,
                              hipStream_t stream) {
    const float* x   = (const float*)d_in[0];
    const int*   ei  = (const int*)d_in[1];
    const float* W1  = (const float*)d_in[2];
    const float* a1s = (const float*)d_in[3];
    const float* a1d = (const float*)d_in[4];
    const float* b1  = (const float*)d_in[5];
    const float* l1W = (const float*)d_in[6];
    const float* l1b = (const float*)d_in[7];
    const float* W2  = (const float*)d_in[8];
    const float* a2s = (const float*)d_in[9];
    const float* a2d = (const float*)d_in[10];
    const float* b2  = (const float*)d_in[11];
    const float* l2W = (const float*)d_in[12];
    const float* l2b = (const float*)d_in[13];
    const float* W3  = (const float*)d_in[14];
    const float* a3s = (const float*)d_in[15];
    const float* a3d = (const float*)d_in[16];
    const float* b3  = (const float*)d_in[17];
    const float* l3W = (const float*)d_in[18];
    const float* l3b = (const float*)d_in[19];

    const int N  = in_sizes[0] / 128;
    const int E  = in_sizes[1] / 2;
    const int ET = E + N;

    unsigned short* Xb = (unsigned short*)d_ws;           // N*128 bf16
    unsigned short* Hb = Xb + (size_t)N * 128;            // N*256 bf16
    unsigned short* BT = Hb + (size_t)N * 256;            // 320*128 bf16
    float* asrc = (float*)(BT + 320 * 128);               // N*4
    float* adst = asrc + (size_t)N * 4;                   // N*4
    float* P    = adst + (size_t)N * 4;                   // ET*4
    int* deg    = (int*)(P + (size_t)ET * 4);             // N
    int* cur    = deg + N;                                // N (adjacent for one memset)
    int* rowptr = cur + N;                                // N
    int* bsum   = rowptr + N;                             // 256
    int2* adjdst = (int2*)(bsum + 256);                   // ET int2

    const int nScanBlocks = (N + 255) / 256;
    int etBlocks   = (ET + 255) / 256;
    int waveBlocks = (N * 64 + 255) / 256;
    int rowBlocks  = (N + 63) / 64;

    // ---------- CSR build (shared by all 3 layers) ----------
    hipMemsetAsync(deg, 0, (size_t)N * 2 * 4, stream);    // deg + cur
    deg_hist4<<<(E / 4 + 256) / 256, 256, 0, stream>>>(ei + E, E, deg);
    scan_block<<<nScanBlocks, 256, 0, stream>>>(deg, rowptr, bsum, N);
    scan_bsum<<<1, 256, 0, stream>>>(bsum, nScanBlocks);
    scan_add<<<nScanBlocks, 256, 0, stream>>>(rowptr, bsum, N);
    csr_fill_bucket<<<512, 256, 0, stream>>>(ei, E, N, rowptr, cur, adjdst);

    castX<<<(N * 32 + 255) / 256, 256, 0, stream>>>(x, Xb, N * 32);

    // ---------- layer 1 ----------
    packB12<<<(320 * 128 + 255) / 256, 256, 0, stream>>>(W1, l1W, a1s, a1d, BT);
    mfma_gemm<<<dim3(5, rowBlocks), 256, 0, stream>>>(Xb, BT, Hb, asrc, adst, N, 256);
    edge_w<<<etBlocks, 256, 0, stream>>>(adjdst, ET, asrc, adst, P);
    gat_gather128<<<waveBlocks, 256, 0, stream>>>(rowptr, adjdst, ET, P, Hb, b1, l1b, Xb, N);

    // ---------- layer 2 ----------
    packB12<<<(320 * 128 + 255) / 256, 256, 0, stream>>>(W2, l2W, a2s, a2d, BT);
    mfma_gemm<<<dim3(5, rowBlocks), 256, 0, stream>>>(Xb, BT, Hb, asrc, adst, N, 256);
    edge_w<<<etBlocks, 256, 0, stream>>>(adjdst, ET, asrc, adst, P);
    gat_gather128<<<waveBlocks, 256, 0, stream>>>(rowptr, adjdst, ET, P, Hb, b2, l2b, Xb, N);

    // ---------- layer 3 ----------
    packB3<<<(128 * 128 + 255) / 256, 256, 0, stream>>>(W3, l3W, a3s, a3d, BT);
    mfma_gemm<<<dim3(2, rowBlocks), 256, 0, stream>>>(Xb, BT, Hb, asrc, adst, N, 64);
    edge_w<<<etBlocks, 256, 0, stream>>>(adjdst, ET, asrc, adst, P);
    gat_gather40<<<waveBlocks, 256, 0, stream>>>(rowptr, adjdst, ET, P, Hb, b3, l3b, (float*)d_out, N);
}